// Round 2
// baseline (1471.245 us; speedup 1.0000x reference)
//
#include <hip/hip_runtime.h>
#include <hip/hip_bf16.h>
#include <math.h>

// ---------------- block reduction helpers (blockDim.x == 256) ----------------
__device__ __forceinline__ float bsum(float v, float* red) {
    int t = threadIdx.x;
    red[t] = v; __syncthreads();
    #pragma unroll
    for (int s = 128; s >= 1; s >>= 1) {
        if (t < s) red[t] += red[t + s];
        __syncthreads();
    }
    float r = red[0]; __syncthreads();
    return r;
}

__device__ __forceinline__ float bmax(float v, float* red) {
    int t = threadIdx.x;
    red[t] = v; __syncthreads();
    #pragma unroll
    for (int s = 128; s >= 1; s >>= 1) {
        if (t < s) red[t] = fmaxf(red[t], red[t + s]);
        __syncthreads();
    }
    float r = red[0]; __syncthreads();
    return r;
}

// ---------------- generic tiled GEMM ----------------
// C[m,n] = scale * sum_k Aelem(m,k)*Belem(k,n)  (+ bias[n]) (+ relu)
// Aelem(m,k) = TRA ? A[k*lda+m] : A[m*lda+k]
// Belem(k,n) = BNT ? B[n*ldb+k] : B[k*ldb+n]
// EPI: 0 = none, 1 = +bias, 2 = +bias then relu. All dims multiples of 64.
template<bool TRA, bool BNT, int EPI>
__global__ __launch_bounds__(256) void gemm_k(
    const float* __restrict__ A, int lda,
    const float* __restrict__ B, int ldb,
    const float* __restrict__ bias,
    float* __restrict__ C, int ldc,
    int M, int N, int K, float scale)
{
    __shared__ float As[16][65];
    __shared__ float Bs[16][65];
    const int t  = threadIdx.x;
    const int tx = t & 15, ty = t >> 4;
    const int bm = blockIdx.y * 64, bn = blockIdx.x * 64;

    float acc[4][4] = {};

    for (int k0 = 0; k0 < K; k0 += 16) {
        // ---- stage A tile: As[k][m] ----
        if (!TRA) {
            int m  = t >> 2;
            int kk = (t & 3) * 4;
            const float* ap = A + (size_t)(bm + m) * lda + k0 + kk;
            #pragma unroll
            for (int j = 0; j < 4; ++j) As[kk + j][m] = ap[j];
        } else {
            int kk = t >> 4;
            int m4 = (t & 15) * 4;
            const float* ap = A + (size_t)(k0 + kk) * lda + bm + m4;
            #pragma unroll
            for (int j = 0; j < 4; ++j) As[kk][m4 + j] = ap[j];
        }
        // ---- stage B tile: Bs[k][n] ----
        if (BNT) {
            int n  = t >> 2;
            int kk = (t & 3) * 4;
            const float* bp = B + (size_t)(bn + n) * ldb + k0 + kk;
            #pragma unroll
            for (int j = 0; j < 4; ++j) Bs[kk + j][n] = bp[j];
        } else {
            int kk = t >> 4;
            int n4 = (t & 15) * 4;
            const float* bp = B + (size_t)(k0 + kk) * ldb + bn + n4;
            #pragma unroll
            for (int j = 0; j < 4; ++j) Bs[kk][n4 + j] = bp[j];
        }
        __syncthreads();

        #pragma unroll
        for (int kk = 0; kk < 16; ++kk) {
            float av[4], bv[4];
            #pragma unroll
            for (int i = 0; i < 4; ++i) av[i] = As[kk][ty * 4 + i];
            #pragma unroll
            for (int j = 0; j < 4; ++j) bv[j] = Bs[kk][tx * 4 + j];
            #pragma unroll
            for (int i = 0; i < 4; ++i)
                #pragma unroll
                for (int j = 0; j < 4; ++j) acc[i][j] += av[i] * bv[j];
        }
        __syncthreads();
    }

    #pragma unroll
    for (int i = 0; i < 4; ++i) {
        int row = bm + ty * 4 + i;
        float* cp = C + (size_t)row * ldc + bn;
        #pragma unroll
        for (int j = 0; j < 4; ++j) {
            int col = tx * 4 + j;
            float v = acc[i][j] * scale;
            if (EPI >= 1) v += bias[bn + col];
            if (EPI == 2) v = fmaxf(v, 0.f);
            cp[col] = v;
        }
    }
}

// ---------------- attention: row softmax per head, then head-average ----------------
// S: [2][1024][1024] (pre-scaled by 1/sqrt(hd)); a[n,m] = 0.5*(sm0 + sm1)
__global__ __launch_bounds__(256) void softmax_mean_k(const float* __restrict__ S,
                                                      float* __restrict__ a)
{
    __shared__ float red[256];
    const int n = blockIdx.x, t = threadIdx.x;
    const float* s0 = S + (size_t)n * 1024;
    const float* s1 = S + (size_t)1048576 + (size_t)n * 1024;

    float v0[4], v1[4];
    #pragma unroll
    for (int j = 0; j < 4; ++j) { v0[j] = s0[t + j * 256]; v1[j] = s1[t + j * 256]; }

    float m0 = fmaxf(fmaxf(v0[0], v0[1]), fmaxf(v0[2], v0[3]));
    float m1 = fmaxf(fmaxf(v1[0], v1[1]), fmaxf(v1[2], v1[3]));
    m0 = bmax(m0, red);
    m1 = bmax(m1, red);

    float e0[4], e1[4], sum0 = 0.f, sum1 = 0.f;
    #pragma unroll
    for (int j = 0; j < 4; ++j) {
        e0[j] = __expf(v0[j] - m0); sum0 += e0[j];
        e1[j] = __expf(v1[j] - m1); sum1 += e1[j];
    }
    sum0 = bsum(sum0, red);
    sum1 = bsum(sum1, red);
    float i0 = 0.5f / sum0, i1 = 0.5f / sum1;

    float* ar = a + (size_t)n * 1024;
    #pragma unroll
    for (int j = 0; j < 4; ++j) ar[t + j * 256] = e0[j] * i0 + e1[j] * i1;
}

// ---------------- column standardize (ddof=1) + column softmax ----------------
// Z: [1024][ldz], column j -> Hout[:, joff+j] (ld ldh). One block per column.
__global__ __launch_bounds__(256) void norm_softmax_k(const float* __restrict__ Z, int ldz,
                                                      float* __restrict__ Hout, int ldh,
                                                      int joff)
{
    __shared__ float red[256];
    const int j = blockIdx.x, t = threadIdx.x;

    float x[4];
    #pragma unroll
    for (int i = 0; i < 4; ++i) x[i] = Z[(size_t)(t + i * 256) * ldz + j];

    float s = x[0] + x[1] + x[2] + x[3];
    float mean = bsum(s, red) * (1.f / 1024.f);

    float ss = 0.f;
    #pragma unroll
    for (int i = 0; i < 4; ++i) { float d = x[i] - mean; ss += d * d; }
    float var = bsum(ss, red) * (1.f / 1023.f);
    float inv = 1.f / (sqrtf(var) + 1e-6f);

    float v[4];
    float mx = -3.4e38f;
    #pragma unroll
    for (int i = 0; i < 4; ++i) { v[i] = (x[i] - mean) * inv; mx = fmaxf(mx, v[i]); }
    mx = bmax(mx, red);

    float e[4], es = 0.f;
    #pragma unroll
    for (int i = 0; i < 4; ++i) { e[i] = __expf(v[i] - mx); es += e[i]; }
    es = bsum(es, red);
    float invs = 1.f / es;

    #pragma unroll
    for (int i = 0; i < 4; ++i)
        Hout[(size_t)(t + i * 256) * ldh + joff + j] = e[i] * invs;
}

// ---------------- ent[j] = sum_n H[n,j]*log(H[n,j]) ----------------
__global__ __launch_bounds__(256) void ent_k(const float* __restrict__ H,
                                             float* __restrict__ ent)
{
    __shared__ float red[256];
    const int j = blockIdx.x, t = threadIdx.x;
    float s = 0.f;
    #pragma unroll
    for (int i = 0; i < 4; ++i) {
        float h = H[(size_t)(t + i * 256) * 256 + j];
        s += h * __logf(h);
    }
    s = bsum(s, red);
    if (t == 0) ent[j] = s;
}

// ---------------- C[j,k] = sum_n H[n,j]*log(0.5*(H[n,j]+H[n,k])) ----------------
__global__ __launch_bounds__(256) void jsd_cross_k(const float* __restrict__ H,
                                                   float* __restrict__ C)
{
    __shared__ float hj[8][33];
    __shared__ float hk[8][33];
    const int t = threadIdx.x;
    const int tx = t & 15, ty = t >> 4;
    const int j0 = blockIdx.y * 32, k0 = blockIdx.x * 32;

    float acc[2][2] = {};

    for (int n0 = 0; n0 < 1024; n0 += 8) {
        int nl = t >> 5, c = t & 31;
        hj[nl][c] = H[(size_t)(n0 + nl) * 256 + j0 + c];
        hk[nl][c] = H[(size_t)(n0 + nl) * 256 + k0 + c];
        __syncthreads();
        #pragma unroll
        for (int nn = 0; nn < 8; ++nn) {
            float a0 = hj[nn][ty * 2], a1 = hj[nn][ty * 2 + 1];
            float b0 = hk[nn][tx * 2], b1 = hk[nn][tx * 2 + 1];
            acc[0][0] += a0 * __logf(0.5f * (a0 + b0));
            acc[0][1] += a0 * __logf(0.5f * (a0 + b1));
            acc[1][0] += a1 * __logf(0.5f * (a1 + b0));
            acc[1][1] += a1 * __logf(0.5f * (a1 + b1));
        }
        __syncthreads();
    }
    #pragma unroll
    for (int i = 0; i < 2; ++i)
        #pragma unroll
        for (int jj = 0; jj < 2; ++jj)
            C[(size_t)(j0 + ty * 2 + i) * 256 + k0 + tx * 2 + jj] = acc[i][jj];
}

// ---------------- jm -> standardize -> softmax -> w  (one block of 256) ----------------
__global__ __launch_bounds__(256) void jmw_k(const float* __restrict__ C,
                                             const float* __restrict__ ent,
                                             float* __restrict__ w)
{
    __shared__ float red[256];
    const int k = threadIdx.x;
    float e = ent[k];
    float esum = bsum(e, red);

    float cm = 0.f, rm = 0.f;
    for (int j = 0; j < 256; ++j) {
        cm += C[(size_t)j * 256 + k];
        rm += C[(size_t)k * 256 + j];
    }
    float jm = 0.5f * (esum * (1.f / 256.f) + e - (cm + rm) * (1.f / 256.f));

    float mean = bsum(jm, red) * (1.f / 256.f);
    float d = jm - mean;
    float var = bsum(d * d, red) * (1.f / 255.f);
    float v = d / (sqrtf(var) + 1e-6f);

    float mx = bmax(v, red);
    float ex = __expf(v - mx);
    float s = bsum(ex, red);
    w[k] = ex / s;
}

// ---------------- Hw[n,j] = H[n,j]*w[j] ----------------
__global__ __launch_bounds__(256) void hw_k(const float* __restrict__ H,
                                            const float* __restrict__ w,
                                            float* __restrict__ Hw)
{
    int i = blockIdx.x * 256 + threadIdx.x;
    Hw[i] = H[i] * w[i & 255];
}

// ---------------- out = x + elu(B) ----------------
__global__ __launch_bounds__(256) void out_x_k(const float* __restrict__ x,
                                               const float* __restrict__ B,
                                               float* __restrict__ out)
{
    int i = blockIdx.x * 256 + threadIdx.x;
    float b = B[i];
    float e = b > 0.f ? b : (__expf(b) - 1.f);
    out[i] = x[i] + e;
}

__global__ __launch_bounds__(256) void copy_k(const float* __restrict__ src,
                                              float* __restrict__ dst)
{
    int i = blockIdx.x * 256 + threadIdx.x;
    dst[i] = src[i];
}

// ---------------- launch ----------------
#define GEMM(TRA, BNT, EPI, Aptr, lda, Bptr, ldb, biasptr, Cptr, ldc, M, N, K, scale) \
    gemm_k<TRA, BNT, EPI><<<dim3((N) / 64, (M) / 64), 256, 0, stream>>>(              \
        Aptr, lda, Bptr, ldb, biasptr, Cptr, ldc, M, N, K, scale)

extern "C" void kernel_launch(void* const* d_in, const int* in_sizes, int n_in,
                              void* d_out, int out_size, void* d_ws, size_t ws_size,
                              hipStream_t stream) {
    const float* x_time = (const float*)d_in[0];
    const float* x_news = (const float*)d_in[1];
    const float* f1w = (const float*)d_in[34];
    const float* f1b = (const float*)d_in[35];
    const float* f2w = (const float*)d_in[36];
    const float* f2b = (const float*)d_in[37];
    const float* theta_t = (const float*)d_in[38];
    const float* theta_n = (const float*)d_in[39];
    float* out = (float*)d_out;

    float* ws = (float*)d_ws;
    float* qf   = ws;                 // 524288
    float* kf   = qf + 524288;        // 524288
    float* S    = kf + 524288;        // 2097152  (2 heads x 1024 x 1024)
    float* a    = S + 2097152;        // 1048576
    float* z1   = a + 1048576;        // 262144
    float* z2   = z1 + 262144;        // 262144
    float* Hcat = z2 + 262144;        // 1048576  (1024 x 1024, 4 tag column-blocks)
    float* Hbuf = Hcat + 1048576;     // 262144   (1024 x 256, final H)
    // aliased (free after their producers are done):
    float* entv = z1;                 // 256      (z1 free after fusion MLP)
    float* Cb   = z1 + 256;           // 65536
    float* wv   = z1 + 256 + 65536;   // 256
    float* Hw   = a;                  // 262144   (a free after tag loop)
    float* G    = qf;                 // 131072   (qf/kf free after tag loop)
    float* P    = qf + 131072;        // 524288
    float* Bt   = S;                  // 524288   (S free after tag loop)

    // 4 MHSA blocks: (q_src, kv_src, input-base-index)
    const float* qsrc[4]  = {x_time, x_news, x_time, x_news};
    const float* kvsrc[4] = {x_time, x_news, x_news, x_time};
    const int    base[4]  = {2, 10, 18, 26};

    for (int tg = 0; tg < 4; ++tg) {
        const float* wq  = (const float*)d_in[base[tg] + 0];
        const float* wk  = (const float*)d_in[base[tg] + 1];
        const float* bq  = (const float*)d_in[base[tg] + 2];
        const float* bk  = (const float*)d_in[base[tg] + 3];
        const float* h1w = (const float*)d_in[base[tg] + 4];
        const float* h1b = (const float*)d_in[base[tg] + 5];
        const float* h2w = (const float*)d_in[base[tg] + 6];
        const float* h2b = (const float*)d_in[base[tg] + 7];

        // q = x @ wq^T + bq ; k = x @ wk^T + bk     [1024 x 512]
        GEMM(false, true, 1, qsrc[tg], 512, wq, 512, bq, qf, 512, 1024, 512, 512, 1.f);
        GEMM(false, true, 1, kvsrc[tg], 512, wk, 512, bk, kf, 512, 1024, 512, 512, 1.f);
        // S_h = (Q_h K_h^T) / 16     [1024 x 1024] per head
        GEMM(false, true, 0, qf, 512, kf, 512, nullptr, S, 1024, 1024, 1024, 256, 0.0625f);
        GEMM(false, true, 0, qf + 256, 512, kf + 256, 512, nullptr, S + 1048576, 1024, 1024, 1024, 256, 0.0625f);
        // a = mean_h softmax_m(S_h)
        softmax_mean_k<<<1024, 256, 0, stream>>>(S, a);
        // incidence MLP
        GEMM(false, true, 2, a, 1024, h1w, 1024, h1b, z1, 256, 1024, 256, 1024, 1.f);
        GEMM(false, true, 1, z1, 256, h2w, 256, h2b, z2, 256, 1024, 256, 256, 1.f);
        // norm_softmax -> Hcat[:, tg*256 : tg*256+256]
        norm_softmax_k<<<256, 256, 0, stream>>>(z2, 256, Hcat, 1024, tg * 256);
    }

    // fusion MLP + norm_softmax -> H
    GEMM(false, true, 2, Hcat, 1024, f1w, 1024, f1b, z1, 256, 1024, 256, 1024, 1.f);
    GEMM(false, true, 1, z1, 256, f2w, 256, f2b, z2, 256, 1024, 256, 256, 1.f);
    norm_softmax_k<<<256, 256, 0, stream>>>(z2, 256, Hbuf, 256, 0);

    // JSD -> jm -> w   (z1 is now free; entv/Cb/wv alias it)
    ent_k<<<256, 256, 0, stream>>>(Hbuf, entv);
    jsd_cross_k<<<dim3(8, 8), 256, 0, stream>>>(Hbuf, Cb);
    jmw_k<<<1, 256, 0, stream>>>(Cb, entv, wv);
    hw_k<<<1024, 256, 0, stream>>>(Hbuf, wv, Hw);

    // xt' = xt + elu((H*w) @ (H^T @ xt) @ theta_t)
    GEMM(true, false, 0, Hbuf, 256, x_time, 512, nullptr, G, 512, 256, 512, 1024, 1.f);
    GEMM(false, false, 0, Hw, 256, G, 512, nullptr, P, 512, 1024, 512, 256, 1.f);
    GEMM(false, false, 0, P, 512, theta_t, 512, nullptr, Bt, 512, 1024, 512, 512, 1.f);
    out_x_k<<<2048, 256, 0, stream>>>(x_time, Bt, out);

    // xn' = xn + elu((H*w) @ (H^T @ xn) @ theta_n)
    GEMM(true, false, 0, Hbuf, 256, x_news, 512, nullptr, G, 512, 256, 512, 1024, 1.f);
    GEMM(false, false, 0, Hw, 256, G, 512, nullptr, P, 512, 1024, 512, 256, 1.f);
    GEMM(false, false, 0, P, 512, theta_n, 512, nullptr, Bt, 512, 1024, 512, 512, 1.f);
    out_x_k<<<2048, 256, 0, stream>>>(x_news, Bt, out + 524288);

    // H output
    copy_k<<<1024, 256, 0, stream>>>(Hbuf, out + 1048576);
}

// Round 3
// 902.906 us; speedup vs baseline: 1.6295x; 1.6295x over previous
//
#include <hip/hip_runtime.h>
#include <hip/hip_bf16.h>
#include <math.h>

typedef __attribute__((ext_vector_type(8))) short bf16x8;
typedef __attribute__((ext_vector_type(4))) float f32x4;

__device__ __forceinline__ short f2bf(float f) {
    unsigned u = __float_as_uint(f);
    u += 0x7fffu + ((u >> 16) & 1u);
    return (short)(u >> 16);
}

// ---------------- block reduction helpers (blockDim.x == 256) ----------------
__device__ __forceinline__ float bsum(float v, float* red) {
    int t = threadIdx.x;
    red[t] = v; __syncthreads();
    #pragma unroll
    for (int s = 128; s >= 1; s >>= 1) {
        if (t < s) red[t] += red[t + s];
        __syncthreads();
    }
    float r = red[0]; __syncthreads();
    return r;
}

__device__ __forceinline__ float bmax(float v, float* red) {
    int t = threadIdx.x;
    red[t] = v; __syncthreads();
    #pragma unroll
    for (int s = 128; s >= 1; s >>= 1) {
        if (t < s) red[t] = fmaxf(red[t], red[t + s]);
        __syncthreads();
    }
    float r = red[0]; __syncthreads();
    return r;
}

// ---------------- MFMA bf16 GEMM ----------------
// C[m,n] = scale * sum_k Aelem(m,k)*Belem(k,n)  (+epilogue)
// TRA: A stored K×M (lda = M-stride). else A is M×K row-major.
// TRB: B stored K×N (ldb = N-stride). else B is N×K row-major (i.e. B^T).
// EPI: 0 none, 1 +bias, 2 +bias+relu, 3 out = addsrc + elu(v)
// Tile 64x64, BK=32, 4 waves each 32x32 via mfma_f32_16x16x32_bf16.
// LDS rows padded to 40 halves (80B, 16B-aligned, 2-way bank alias = free).
template<bool TRA, bool TRB, int EPI>
__global__ __launch_bounds__(256) void gemm_mfma_k(
    const float* __restrict__ A, int lda,
    const float* __restrict__ B, int ldb,
    const float* __restrict__ bias,
    const float* __restrict__ addsrc,
    float* __restrict__ C, int ldc,
    int M, int N, int K, float scale)
{
    __shared__ __align__(16) short As[64 * 40];
    __shared__ __align__(16) short Bs[64 * 40];
    const int t = threadIdx.x;
    const int lane = t & 63;
    const int w = t >> 6, wm = w >> 1, wn = w & 1;
    const int bm = blockIdx.y * 64, bn = blockIdx.x * 64;
    const int l15 = lane & 15, l4 = lane >> 4;

    f32x4 acc[2][2];
    #pragma unroll
    for (int i = 0; i < 2; ++i)
        #pragma unroll
        for (int j = 0; j < 2; ++j)
            #pragma unroll
            for (int r = 0; r < 4; ++r) acc[i][j][r] = 0.f;

    for (int k0 = 0; k0 < K; k0 += 32) {
        // ---- stage A ----
        if (!TRA) {
            #pragma unroll
            for (int p = 0; p < 2; ++p) {
                int row = (t >> 3) + p * 32;
                int c4 = (t & 7) * 4;
                const float4 v = *reinterpret_cast<const float4*>(
                    A + (size_t)(bm + row) * lda + k0 + c4);
                short4 s4 = make_short4(f2bf(v.x), f2bf(v.y), f2bf(v.z), f2bf(v.w));
                *reinterpret_cast<short4*>(&As[row * 40 + c4]) = s4;
            }
        } else {
            #pragma unroll
            for (int p = 0; p < 2; ++p) {
                int kk = (t >> 4) + p * 16;
                int m4 = (t & 15) * 4;
                const float4 v = *reinterpret_cast<const float4*>(
                    A + (size_t)(k0 + kk) * lda + bm + m4);
                As[(m4 + 0) * 40 + kk] = f2bf(v.x);
                As[(m4 + 1) * 40 + kk] = f2bf(v.y);
                As[(m4 + 2) * 40 + kk] = f2bf(v.z);
                As[(m4 + 3) * 40 + kk] = f2bf(v.w);
            }
        }
        // ---- stage B ----
        if (!TRB) {
            #pragma unroll
            for (int p = 0; p < 2; ++p) {
                int row = (t >> 3) + p * 32;
                int c4 = (t & 7) * 4;
                const float4 v = *reinterpret_cast<const float4*>(
                    B + (size_t)(bn + row) * ldb + k0 + c4);
                short4 s4 = make_short4(f2bf(v.x), f2bf(v.y), f2bf(v.z), f2bf(v.w));
                *reinterpret_cast<short4*>(&Bs[row * 40 + c4]) = s4;
            }
        } else {
            #pragma unroll
            for (int p = 0; p < 2; ++p) {
                int kk = (t >> 4) + p * 16;
                int n4 = (t & 15) * 4;
                const float4 v = *reinterpret_cast<const float4*>(
                    B + (size_t)(k0 + kk) * ldb + bn + n4);
                Bs[(n4 + 0) * 40 + kk] = f2bf(v.x);
                Bs[(n4 + 1) * 40 + kk] = f2bf(v.y);
                Bs[(n4 + 2) * 40 + kk] = f2bf(v.z);
                Bs[(n4 + 3) * 40 + kk] = f2bf(v.w);
            }
        }
        __syncthreads();

        const bf16x8* Ap = reinterpret_cast<const bf16x8*>(As);
        const bf16x8* Bp = reinterpret_cast<const bf16x8*>(Bs);
        bf16x8 af[2], bf[2];
        #pragma unroll
        for (int mi = 0; mi < 2; ++mi)
            af[mi] = Ap[(wm * 32 + mi * 16 + l15) * 5 + l4];
        #pragma unroll
        for (int ni = 0; ni < 2; ++ni)
            bf[ni] = Bp[(wn * 32 + ni * 16 + l15) * 5 + l4];
        #pragma unroll
        for (int mi = 0; mi < 2; ++mi)
            #pragma unroll
            for (int ni = 0; ni < 2; ++ni)
                acc[mi][ni] = __builtin_amdgcn_mfma_f32_16x16x32_bf16(
                    af[mi], bf[ni], acc[mi][ni], 0, 0, 0);
        __syncthreads();
    }

    #pragma unroll
    for (int mi = 0; mi < 2; ++mi) {
        #pragma unroll
        for (int ni = 0; ni < 2; ++ni) {
            int col = bn + wn * 32 + ni * 16 + l15;
            #pragma unroll
            for (int r = 0; r < 4; ++r) {
                int row = bm + wm * 32 + mi * 16 + l4 * 4 + r;
                float v = acc[mi][ni][r] * scale;
                if (EPI == 1) v += bias[col];
                if (EPI == 2) v = fmaxf(v + bias[col], 0.f);
                if (EPI == 3) {
                    float e = v > 0.f ? v : (__expf(v) - 1.f);
                    v = addsrc[(size_t)row * ldc + col] + e;
                }
                C[(size_t)row * ldc + col] = v;
            }
        }
    }
}

// ---------------- attention: row softmax per head, then head-average ----------------
__global__ __launch_bounds__(256) void softmax_mean_k(const float* __restrict__ S,
                                                      float* __restrict__ a)
{
    __shared__ float red[256];
    const int n = blockIdx.x, t = threadIdx.x;
    const float* s0 = S + (size_t)n * 1024;
    const float* s1 = S + (size_t)1048576 + (size_t)n * 1024;

    float v0[4], v1[4];
    #pragma unroll
    for (int j = 0; j < 4; ++j) { v0[j] = s0[t + j * 256]; v1[j] = s1[t + j * 256]; }

    float m0 = fmaxf(fmaxf(v0[0], v0[1]), fmaxf(v0[2], v0[3]));
    float m1 = fmaxf(fmaxf(v1[0], v1[1]), fmaxf(v1[2], v1[3]));
    m0 = bmax(m0, red);
    m1 = bmax(m1, red);

    float e0[4], e1[4], sum0 = 0.f, sum1 = 0.f;
    #pragma unroll
    for (int j = 0; j < 4; ++j) {
        e0[j] = __expf(v0[j] - m0); sum0 += e0[j];
        e1[j] = __expf(v1[j] - m1); sum1 += e1[j];
    }
    sum0 = bsum(sum0, red);
    sum1 = bsum(sum1, red);
    float i0 = 0.5f / sum0, i1 = 0.5f / sum1;

    float* ar = a + (size_t)n * 1024;
    #pragma unroll
    for (int j = 0; j < 4; ++j) ar[t + j * 256] = e0[j] * i0 + e1[j] * i1;
}

// ---------------- column standardize (ddof=1) + column softmax ----------------
__global__ __launch_bounds__(256) void norm_softmax_k(const float* __restrict__ Z, int ldz,
                                                      float* __restrict__ Hout, int ldh,
                                                      int joff)
{
    __shared__ float red[256];
    const int j = blockIdx.x, t = threadIdx.x;

    float x[4];
    #pragma unroll
    for (int i = 0; i < 4; ++i) x[i] = Z[(size_t)(t + i * 256) * ldz + j];

    float s = x[0] + x[1] + x[2] + x[3];
    float mean = bsum(s, red) * (1.f / 1024.f);

    float ss = 0.f;
    #pragma unroll
    for (int i = 0; i < 4; ++i) { float d = x[i] - mean; ss += d * d; }
    float var = bsum(ss, red) * (1.f / 1023.f);
    float inv = 1.f / (sqrtf(var) + 1e-6f);

    float v[4];
    float mx = -3.4e38f;
    #pragma unroll
    for (int i = 0; i < 4; ++i) { v[i] = (x[i] - mean) * inv; mx = fmaxf(mx, v[i]); }
    mx = bmax(mx, red);

    float e[4], es = 0.f;
    #pragma unroll
    for (int i = 0; i < 4; ++i) { e[i] = __expf(v[i] - mx); es += e[i]; }
    es = bsum(es, red);
    float invs = 1.f / es;

    #pragma unroll
    for (int i = 0; i < 4; ++i)
        Hout[(size_t)(t + i * 256) * ldh + joff + j] = e[i] * invs;
}

// ---------------- ent[j] = sum_n H[n,j]*log(H[n,j]) ----------------
__global__ __launch_bounds__(256) void ent_k(const float* __restrict__ H,
                                             float* __restrict__ ent)
{
    __shared__ float red[256];
    const int j = blockIdx.x, t = threadIdx.x;
    float s = 0.f;
    #pragma unroll
    for (int i = 0; i < 4; ++i) {
        float h = H[(size_t)(t + i * 256) * 256 + j];
        s += h * __logf(h);
    }
    s = bsum(s, red);
    if (t == 0) ent[j] = s;
}

// ---------------- Cpart[s][j][k] = sum_{n in slab s} H[n,j]*log(0.5*(H[n,j]+H[n,k])) ----
__global__ __launch_bounds__(256) void jsd_part_k(const float* __restrict__ H,
                                                  float* __restrict__ Cpart)
{
    __shared__ float hj[8][33];
    __shared__ float hk[8][33];
    const int t = threadIdx.x;
    const int tx = t & 15, ty = t >> 4;
    const int j0 = blockIdx.y * 32, k0 = blockIdx.x * 32;
    const int nbase = blockIdx.z * 128;

    float acc[2][2] = {};

    for (int c = 0; c < 16; ++c) {
        int n0 = nbase + c * 8;
        int nl = t >> 5, cc = t & 31;
        hj[nl][cc] = H[(size_t)(n0 + nl) * 256 + j0 + cc];
        hk[nl][cc] = H[(size_t)(n0 + nl) * 256 + k0 + cc];
        __syncthreads();
        #pragma unroll
        for (int nn = 0; nn < 8; ++nn) {
            float a0 = hj[nn][ty * 2], a1 = hj[nn][ty * 2 + 1];
            float b0 = hk[nn][tx * 2], b1 = hk[nn][tx * 2 + 1];
            acc[0][0] += a0 * __logf(0.5f * (a0 + b0));
            acc[0][1] += a0 * __logf(0.5f * (a0 + b1));
            acc[1][0] += a1 * __logf(0.5f * (a1 + b0));
            acc[1][1] += a1 * __logf(0.5f * (a1 + b1));
        }
        __syncthreads();
    }
    float* Cp = Cpart + (size_t)blockIdx.z * 65536;
    #pragma unroll
    for (int i = 0; i < 2; ++i)
        #pragma unroll
        for (int jj = 0; jj < 2; ++jj)
            Cp[(size_t)(j0 + ty * 2 + i) * 256 + k0 + tx * 2 + jj] = acc[i][jj];
}

__global__ __launch_bounds__(256) void jsd_reduce_k(const float* __restrict__ Cpart,
                                                    float* __restrict__ C)
{
    int i = blockIdx.x * 256 + threadIdx.x;
    float s = 0.f;
    #pragma unroll
    for (int sl = 0; sl < 8; ++sl) s += Cpart[(size_t)sl * 65536 + i];
    C[i] = s;
}

// ---------------- per-k row/col sums of C ----------------
__global__ __launch_bounds__(256) void rc_k(const float* __restrict__ C,
                                            float* __restrict__ cmv,
                                            float* __restrict__ rmv)
{
    __shared__ float red[256];
    const int k = blockIdx.x, j = threadIdx.x;
    float cm = C[(size_t)j * 256 + k];
    float rm = C[(size_t)k * 256 + j];
    cm = bsum(cm, red);
    rm = bsum(rm, red);
    if (j == 0) { cmv[k] = cm; rmv[k] = rm; }
}

// ---------------- jm -> standardize -> softmax -> w  (one block of 256) ----------------
__global__ __launch_bounds__(256) void jmw_k(const float* __restrict__ cmv,
                                             const float* __restrict__ rmv,
                                             const float* __restrict__ ent,
                                             float* __restrict__ w)
{
    __shared__ float red[256];
    const int k = threadIdx.x;
    float e = ent[k];
    float esum = bsum(e, red);

    float jm = 0.5f * (esum * (1.f / 256.f) + e - (cmv[k] + rmv[k]) * (1.f / 256.f));

    float mean = bsum(jm, red) * (1.f / 256.f);
    float d = jm - mean;
    float var = bsum(d * d, red) * (1.f / 255.f);
    float v = d / (sqrtf(var) + 1e-6f);

    float mx = bmax(v, red);
    float ex = __expf(v - mx);
    float s = bsum(ex, red);
    w[k] = ex / s;
}

// ---------------- Hw[n,j] = H[n,j]*w[j] ----------------
__global__ __launch_bounds__(256) void hw_k(const float* __restrict__ H,
                                            const float* __restrict__ w,
                                            float* __restrict__ Hw)
{
    int i = blockIdx.x * 256 + threadIdx.x;
    Hw[i] = H[i] * w[i & 255];
}

__global__ __launch_bounds__(256) void copy_k(const float* __restrict__ src,
                                              float* __restrict__ dst)
{
    int i = blockIdx.x * 256 + threadIdx.x;
    dst[i] = src[i];
}

// ---------------- launch ----------------
#define GEMM(TRA, TRB, EPI, Aptr, lda, Bptr, ldb, biasptr, addptr, Cptr, ldc, M, N, K, scale) \
    gemm_mfma_k<TRA, TRB, EPI><<<dim3((N) / 64, (M) / 64), 256, 0, stream>>>(                 \
        Aptr, lda, Bptr, ldb, biasptr, addptr, Cptr, ldc, M, N, K, scale)

extern "C" void kernel_launch(void* const* d_in, const int* in_sizes, int n_in,
                              void* d_out, int out_size, void* d_ws, size_t ws_size,
                              hipStream_t stream) {
    const float* x_time = (const float*)d_in[0];
    const float* x_news = (const float*)d_in[1];
    const float* f1w = (const float*)d_in[34];
    const float* f1b = (const float*)d_in[35];
    const float* f2w = (const float*)d_in[36];
    const float* f2b = (const float*)d_in[37];
    const float* theta_t = (const float*)d_in[38];
    const float* theta_n = (const float*)d_in[39];
    float* out = (float*)d_out;

    float* ws = (float*)d_ws;
    float* qf   = ws;                 // 524288
    float* kf   = qf + 524288;        // 524288
    float* S    = kf + 524288;        // 2097152  (2 heads x 1024 x 1024)
    float* a    = S + 2097152;        // 1048576
    float* z1   = a + 1048576;        // 262144
    float* z2   = z1 + 262144;        // 262144
    float* Hcat = z2 + 262144;        // 1048576  (1024 x 1024, 4 tag column-blocks)
    float* Hbuf = Hcat + 1048576;     // 262144   (1024 x 256, final H)
    // aliases (free after their producers finish; stream-ordered):
    float* entv  = z1;                // 256     (z1 free after fusion MLP)
    float* Cb    = z1 + 256;          // 65536
    float* wv    = z1 + 256 + 65536;  // 256
    float* cmv   = wv + 256;          // 256
    float* rmv   = cmv + 256;         // 256
    float* Cpart = S;                 // 524288  (S free after tag loop)
    float* Hw    = a;                 // 262144  (a free after tag loop)
    float* G     = qf;                // 131072  (qf/kf free after tag loop)
    float* P     = kf;                // 524288

    const float* qsrc[4]  = {x_time, x_news, x_time, x_news};
    const float* kvsrc[4] = {x_time, x_news, x_news, x_time};
    const int    base[4]  = {2, 10, 18, 26};

    for (int tg = 0; tg < 4; ++tg) {
        const float* wq  = (const float*)d_in[base[tg] + 0];
        const float* wk  = (const float*)d_in[base[tg] + 1];
        const float* bq  = (const float*)d_in[base[tg] + 2];
        const float* bk  = (const float*)d_in[base[tg] + 3];
        const float* h1w = (const float*)d_in[base[tg] + 4];
        const float* h1b = (const float*)d_in[base[tg] + 5];
        const float* h2w = (const float*)d_in[base[tg] + 6];
        const float* h2b = (const float*)d_in[base[tg] + 7];

        // q = x @ wq^T + bq ; k = x @ wk^T + bk     [1024 x 512]
        GEMM(false, false, 1, qsrc[tg], 512, wq, 512, bq, nullptr, qf, 512, 1024, 512, 512, 1.f);
        GEMM(false, false, 1, kvsrc[tg], 512, wk, 512, bk, nullptr, kf, 512, 1024, 512, 512, 1.f);
        // S_h = (Q_h K_h^T) / 16     [1024 x 1024] per head
        GEMM(false, false, 0, qf, 512, kf, 512, nullptr, nullptr, S, 1024, 1024, 1024, 256, 0.0625f);
        GEMM(false, false, 0, qf + 256, 512, kf + 256, 512, nullptr, nullptr, S + 1048576, 1024, 1024, 1024, 256, 0.0625f);
        // a = mean_h softmax_m(S_h)
        softmax_mean_k<<<1024, 256, 0, stream>>>(S, a);
        // incidence MLP
        GEMM(false, false, 2, a, 1024, h1w, 1024, h1b, nullptr, z1, 256, 1024, 256, 1024, 1.f);
        GEMM(false, false, 1, z1, 256, h2w, 256, h2b, nullptr, z2, 256, 1024, 256, 256, 1.f);
        // norm_softmax -> Hcat[:, tg*256 : tg*256+256]
        norm_softmax_k<<<256, 256, 0, stream>>>(z2, 256, Hcat, 1024, tg * 256);
    }

    // fusion MLP + norm_softmax -> H
    GEMM(false, false, 2, Hcat, 1024, f1w, 1024, f1b, nullptr, z1, 256, 1024, 256, 1024, 1.f);
    GEMM(false, false, 1, z1, 256, f2w, 256, f2b, nullptr, z2, 256, 1024, 256, 256, 1.f);
    norm_softmax_k<<<256, 256, 0, stream>>>(z2, 256, Hbuf, 256, 0);

    // JSD -> jm -> w
    ent_k<<<256, 256, 0, stream>>>(Hbuf, entv);
    jsd_part_k<<<dim3(8, 8, 8), 256, 0, stream>>>(Hbuf, Cpart);
    jsd_reduce_k<<<256, 256, 0, stream>>>(Cpart, Cb);
    rc_k<<<256, 256, 0, stream>>>(Cb, cmv, rmv);
    jmw_k<<<1, 256, 0, stream>>>(cmv, rmv, entv, wv);
    hw_k<<<1024, 256, 0, stream>>>(Hbuf, wv, Hw);

    // xt' = xt + elu((H*w) @ (H^T @ xt) @ theta_t)
    GEMM(true, true, 0, Hbuf, 256, x_time, 512, nullptr, nullptr, G, 512, 256, 512, 1024, 1.f);
    GEMM(false, true, 0, Hw, 256, G, 512, nullptr, nullptr, P, 512, 1024, 512, 256, 1.f);
    GEMM(false, true, 3, P, 512, theta_t, 512, nullptr, x_time, out, 512, 1024, 512, 512, 1.f);

    // xn' = xn + elu((H*w) @ (H^T @ xn) @ theta_n)
    GEMM(true, true, 0, Hbuf, 256, x_news, 512, nullptr, nullptr, G, 512, 256, 512, 1024, 1.f);
    GEMM(false, true, 0, Hw, 256, G, 512, nullptr, nullptr, P, 512, 1024, 512, 256, 1.f);
    GEMM(false, true, 3, P, 512, theta_n, 512, nullptr, x_news, out + 524288, 512, 1024, 512, 512, 1.f);

    // H output
    copy_k<<<1024, 256, 0, stream>>>(Hbuf, out + 1048576);
}

// Round 4
// 273.682 us; speedup vs baseline: 5.3757x; 3.2991x over previous
//
#include <hip/hip_runtime.h>
#include <hip/hip_bf16.h>
#include <math.h>

typedef __attribute__((ext_vector_type(8))) short bf16x8;
typedef __attribute__((ext_vector_type(8))) short short8;
typedef __attribute__((ext_vector_type(4))) float f32x4;

__device__ __forceinline__ short f2bf(float f) {
    unsigned u = __float_as_uint(f);
    u += 0x7fffu + ((u >> 16) & 1u);
    return (short)(u >> 16);
}
__device__ __forceinline__ float bf2f(short s) {
    return __uint_as_float(((unsigned)(unsigned short)s) << 16);
}

// ---------------- block reduction helpers (blockDim.x == 256) ----------------
__device__ __forceinline__ float bsum(float v, float* red) {
    int t = threadIdx.x;
    red[t] = v; __syncthreads();
    #pragma unroll
    for (int s = 128; s >= 1; s >>= 1) {
        if (t < s) red[t] += red[t + s];
        __syncthreads();
    }
    float r = red[0]; __syncthreads();
    return r;
}

__device__ __forceinline__ float bmax(float v, float* red) {
    int t = threadIdx.x;
    red[t] = v; __syncthreads();
    #pragma unroll
    for (int s = 128; s >= 1; s >>= 1) {
        if (t < s) red[t] = fmaxf(red[t], red[t + s]);
        __syncthreads();
    }
    float r = red[0]; __syncthreads();
    return r;
}

// ---------------- batched MFMA bf16 GEMM ----------------
// Per batch z: C[m,n] = scale * sum_k Aelem(m,k)*Belem(k,n)  (+epilogue)
// TA/TB/TC: float or short(bf16 bits). TRA/TRB: operand stored K-major (fp32 only).
// EPI: 0 none, 1 +bias, 2 +bias+relu, 3 out = add + elu(v)
// Tile 64x64, BK=32, 4 waves each 32x32 via mfma_f32_16x16x32_bf16.
struct Batch8 {
    const void* A[8];
    const void* B[8];
    const float* bias[8];
    const float* add[8];
    void* C[8];
};

template<typename TA, typename TB, typename TC, bool TRA, bool TRB, int EPI>
__global__ __launch_bounds__(256) void gemm_b_k(Batch8 bp, int lda, int ldb, int ldc,
                                                int K, float scale)
{
    __shared__ __align__(16) short As[64 * 40];
    __shared__ __align__(16) short Bs[64 * 40];
    const int t = threadIdx.x;
    const int lane = t & 63;
    const int w = t >> 6, wm = w >> 1, wn = w & 1;
    const int bm = blockIdx.y * 64, bn = blockIdx.x * 64;
    const int l15 = lane & 15, l4 = lane >> 4;
    const TA* __restrict__ A = (const TA*)bp.A[blockIdx.z];
    const TB* __restrict__ B = (const TB*)bp.B[blockIdx.z];

    f32x4 acc[2][2];
    #pragma unroll
    for (int i = 0; i < 2; ++i)
        #pragma unroll
        for (int j = 0; j < 2; ++j)
            #pragma unroll
            for (int r = 0; r < 4; ++r) acc[i][j][r] = 0.f;

    for (int k0 = 0; k0 < K; k0 += 32) {
        // ---- stage A ----
        if constexpr (!TRA) {
            if constexpr (sizeof(TA) == 4) {
                #pragma unroll
                for (int p = 0; p < 2; ++p) {
                    int row = (t >> 3) + p * 32;
                    int c4 = (t & 7) * 4;
                    const float4 v = *reinterpret_cast<const float4*>(
                        A + (size_t)(bm + row) * lda + k0 + c4);
                    short4 s4 = make_short4(f2bf(v.x), f2bf(v.y), f2bf(v.z), f2bf(v.w));
                    *reinterpret_cast<short4*>(&As[row * 40 + c4]) = s4;
                }
            } else {
                int row = t >> 2, c8 = (t & 3) * 8;
                short8 v = *reinterpret_cast<const short8*>(
                    A + (size_t)(bm + row) * lda + k0 + c8);
                *reinterpret_cast<short8*>(&As[row * 40 + c8]) = v;
            }
        } else {
            #pragma unroll
            for (int p = 0; p < 2; ++p) {
                int kk = (t >> 4) + p * 16;
                int m4 = (t & 15) * 4;
                const float4 v = *reinterpret_cast<const float4*>(
                    (const float*)A + (size_t)(k0 + kk) * lda + bm + m4);
                As[(m4 + 0) * 40 + kk] = f2bf(v.x);
                As[(m4 + 1) * 40 + kk] = f2bf(v.y);
                As[(m4 + 2) * 40 + kk] = f2bf(v.z);
                As[(m4 + 3) * 40 + kk] = f2bf(v.w);
            }
        }
        // ---- stage B ----
        if constexpr (!TRB) {
            if constexpr (sizeof(TB) == 4) {
                #pragma unroll
                for (int p = 0; p < 2; ++p) {
                    int row = (t >> 3) + p * 32;
                    int c4 = (t & 7) * 4;
                    const float4 v = *reinterpret_cast<const float4*>(
                        B + (size_t)(bn + row) * ldb + k0 + c4);
                    short4 s4 = make_short4(f2bf(v.x), f2bf(v.y), f2bf(v.z), f2bf(v.w));
                    *reinterpret_cast<short4*>(&Bs[row * 40 + c4]) = s4;
                }
            } else {
                int row = t >> 2, c8 = (t & 3) * 8;
                short8 v = *reinterpret_cast<const short8*>(
                    B + (size_t)(bn + row) * ldb + k0 + c8);
                *reinterpret_cast<short8*>(&Bs[row * 40 + c8]) = v;
            }
        } else {
            #pragma unroll
            for (int p = 0; p < 2; ++p) {
                int kk = (t >> 4) + p * 16;
                int n4 = (t & 15) * 4;
                const float4 v = *reinterpret_cast<const float4*>(
                    (const float*)B + (size_t)(k0 + kk) * ldb + bn + n4);
                Bs[(n4 + 0) * 40 + kk] = f2bf(v.x);
                Bs[(n4 + 1) * 40 + kk] = f2bf(v.y);
                Bs[(n4 + 2) * 40 + kk] = f2bf(v.z);
                Bs[(n4 + 3) * 40 + kk] = f2bf(v.w);
            }
        }
        __syncthreads();

        const bf16x8* Ap = reinterpret_cast<const bf16x8*>(As);
        const bf16x8* Bp = reinterpret_cast<const bf16x8*>(Bs);
        bf16x8 af[2], bfr[2];
        #pragma unroll
        for (int mi = 0; mi < 2; ++mi)
            af[mi] = Ap[(wm * 32 + mi * 16 + l15) * 5 + l4];
        #pragma unroll
        for (int ni = 0; ni < 2; ++ni)
            bfr[ni] = Bp[(wn * 32 + ni * 16 + l15) * 5 + l4];
        #pragma unroll
        for (int mi = 0; mi < 2; ++mi)
            #pragma unroll
            for (int ni = 0; ni < 2; ++ni)
                acc[mi][ni] = __builtin_amdgcn_mfma_f32_16x16x32_bf16(
                    af[mi], bfr[ni], acc[mi][ni], 0, 0, 0);
        __syncthreads();
    }

    const float* bias = bp.bias[blockIdx.z];
    const float* add = bp.add[blockIdx.z];
    TC* __restrict__ C = (TC*)bp.C[blockIdx.z];
    #pragma unroll
    for (int mi = 0; mi < 2; ++mi) {
        #pragma unroll
        for (int ni = 0; ni < 2; ++ni) {
            int col = bn + wn * 32 + ni * 16 + l15;
            #pragma unroll
            for (int r = 0; r < 4; ++r) {
                int row = bm + wm * 32 + mi * 16 + l4 * 4 + r;
                float v = acc[mi][ni][r] * scale;
                if (EPI == 1) v += bias[col];
                if (EPI == 2) v = fmaxf(v + bias[col], 0.f);
                if (EPI == 3) {
                    float e = v > 0.f ? v : (__expf(v) - 1.f);
                    v = add[(size_t)row * ldc + col] + e;
                }
                if constexpr (sizeof(TC) == 4) C[(size_t)row * ldc + col] = v;
                else C[(size_t)row * ldc + col] = f2bf(v);
            }
        }
    }
}

// ---------------- attention softmax + head-mean (bf16 in/out), 2-tag pair ----
// grid.x = 2048: tag = x>>10, row = x&1023. S layout: [tag*2+head][1024][1024] bf16.
__global__ __launch_bounds__(256) void softmax_mean_b(const short* __restrict__ S,
                                                      short* __restrict__ a)
{
    __shared__ float red[256];
    const int g = blockIdx.x, t = threadIdx.x;
    const int tag = g >> 10, row = g & 1023;
    const short* s0 = S + ((size_t)(tag * 2 + 0) << 20) + (size_t)row * 1024 + t * 4;
    const short* s1 = S + ((size_t)(tag * 2 + 1) << 20) + (size_t)row * 1024 + t * 4;

    short4 r0 = *reinterpret_cast<const short4*>(s0);
    short4 r1 = *reinterpret_cast<const short4*>(s1);
    float v0[4] = {bf2f(r0.x), bf2f(r0.y), bf2f(r0.z), bf2f(r0.w)};
    float v1[4] = {bf2f(r1.x), bf2f(r1.y), bf2f(r1.z), bf2f(r1.w)};

    float m0 = fmaxf(fmaxf(v0[0], v0[1]), fmaxf(v0[2], v0[3]));
    float m1 = fmaxf(fmaxf(v1[0], v1[1]), fmaxf(v1[2], v1[3]));
    m0 = bmax(m0, red);
    m1 = bmax(m1, red);

    float e0[4], e1[4], sum0 = 0.f, sum1 = 0.f;
    #pragma unroll
    for (int j = 0; j < 4; ++j) {
        e0[j] = __expf(v0[j] - m0); sum0 += e0[j];
        e1[j] = __expf(v1[j] - m1); sum1 += e1[j];
    }
    sum0 = bsum(sum0, red);
    sum1 = bsum(sum1, red);
    float i0 = 0.5f / sum0, i1 = 0.5f / sum1;

    short4 o;
    o.x = f2bf(e0[0] * i0 + e1[0] * i1);
    o.y = f2bf(e0[1] * i0 + e1[1] * i1);
    o.z = f2bf(e0[2] * i0 + e1[2] * i1);
    o.w = f2bf(e0[3] * i0 + e1[3] * i1);
    *reinterpret_cast<short4*>(a + ((size_t)tag << 20) + (size_t)row * 1024 + t * 4) = o;
}

// ---------------- column standardize (ddof=1) + column softmax, batched ------
// grid: (256 cols, nb batches). Z = Zbase + bz*zstride (fp32 [1024 x 256]).
// Hout[:, bz*joffmul + j], ld ldh. TOUT float or short.
template<typename TOUT>
__global__ __launch_bounds__(256) void norm_softmax_b(const float* __restrict__ Zbase,
                                                      int zstride,
                                                      TOUT* __restrict__ Hout, int ldh,
                                                      int joffmul)
{
    __shared__ float red[256];
    const int j = blockIdx.x, t = threadIdx.x;
    const float* Z = Zbase + (size_t)blockIdx.y * zstride;
    const int joff = blockIdx.y * joffmul;

    float x[4];
    #pragma unroll
    for (int i = 0; i < 4; ++i) x[i] = Z[(size_t)(t + i * 256) * 256 + j];

    float s = x[0] + x[1] + x[2] + x[3];
    float mean = bsum(s, red) * (1.f / 1024.f);

    float ss = 0.f;
    #pragma unroll
    for (int i = 0; i < 4; ++i) { float d = x[i] - mean; ss += d * d; }
    float var = bsum(ss, red) * (1.f / 1023.f);
    float inv = 1.f / (sqrtf(var) + 1e-6f);

    float v[4];
    float mx = -3.4e38f;
    #pragma unroll
    for (int i = 0; i < 4; ++i) { v[i] = (x[i] - mean) * inv; mx = fmaxf(mx, v[i]); }
    mx = bmax(mx, red);

    float e[4], es = 0.f;
    #pragma unroll
    for (int i = 0; i < 4; ++i) { e[i] = __expf(v[i] - mx); es += e[i]; }
    es = bsum(es, red);
    float invs = 1.f / es;

    #pragma unroll
    for (int i = 0; i < 4; ++i) {
        float o = e[i] * invs;
        if constexpr (sizeof(TOUT) == 4)
            Hout[(size_t)(t + i * 256) * ldh + joff + j] = o;
        else
            Hout[(size_t)(t + i * 256) * ldh + joff + j] = f2bf(o);
    }
}

// ---------------- fusion split-K reduce: z1f = bf16(relu(sum_s Cpartf + b)) ---
__global__ __launch_bounds__(256) void freduce_k(const float* __restrict__ Cpartf,
                                                 const float* __restrict__ b,
                                                 short* __restrict__ z1f)
{
    int i = blockIdx.x * 256 + threadIdx.x;
    float s = b[i & 255];
    #pragma unroll
    for (int z = 0; z < 4; ++z) s += Cpartf[(size_t)z * 262144 + i];
    z1f[i] = f2bf(fmaxf(s, 0.f));
}

// ---------------- G split-K reduce ----------------
__global__ __launch_bounds__(256) void g_reduce_k(const float* __restrict__ Gpart,
                                                  float* __restrict__ G)
{
    int chain = blockIdx.y;
    int i = blockIdx.x * 256 + threadIdx.x;
    G[(size_t)chain * 131072 + i] =
        Gpart[(size_t)(chain * 2 + 0) * 131072 + i] +
        Gpart[(size_t)(chain * 2 + 1) * 131072 + i];
}

// ---------------- ent[j] = sum_n H[n,j]*log(H[n,j]) ----------------
__global__ __launch_bounds__(256) void ent_k(const float* __restrict__ H,
                                             float* __restrict__ ent)
{
    __shared__ float red[256];
    const int j = blockIdx.x, t = threadIdx.x;
    float s = 0.f;
    #pragma unroll
    for (int i = 0; i < 4; ++i) {
        float h = H[(size_t)(t + i * 256) * 256 + j];
        s += h * __logf(h);
    }
    s = bsum(s, red);
    if (t == 0) ent[j] = s;
}

// ---------------- Cpart[s][j][k] = sum_{n in slab s} H[n,j]*log(0.5*(H[n,j]+H[n,k]))
__global__ __launch_bounds__(256) void jsd_part_k(const float* __restrict__ H,
                                                  float* __restrict__ Cpart)
{
    __shared__ float hj[8][33];
    __shared__ float hk[8][33];
    const int t = threadIdx.x;
    const int tx = t & 15, ty = t >> 4;
    const int j0 = blockIdx.y * 32, k0 = blockIdx.x * 32;
    const int nbase = blockIdx.z * 128;

    float acc[2][2] = {};

    for (int c = 0; c < 16; ++c) {
        int n0 = nbase + c * 8;
        int nl = t >> 5, cc = t & 31;
        hj[nl][cc] = H[(size_t)(n0 + nl) * 256 + j0 + cc];
        hk[nl][cc] = H[(size_t)(n0 + nl) * 256 + k0 + cc];
        __syncthreads();
        #pragma unroll
        for (int nn = 0; nn < 8; ++nn) {
            float a0 = hj[nn][ty * 2], a1 = hj[nn][ty * 2 + 1];
            float b0 = hk[nn][tx * 2], b1 = hk[nn][tx * 2 + 1];
            acc[0][0] += a0 * __logf(0.5f * (a0 + b0));
            acc[0][1] += a0 * __logf(0.5f * (a0 + b1));
            acc[1][0] += a1 * __logf(0.5f * (a1 + b0));
            acc[1][1] += a1 * __logf(0.5f * (a1 + b1));
        }
        __syncthreads();
    }
    float* Cp = Cpart + (size_t)blockIdx.z * 65536;
    #pragma unroll
    for (int i = 0; i < 2; ++i)
        #pragma unroll
        for (int jj = 0; jj < 2; ++jj)
            Cp[(size_t)(j0 + ty * 2 + i) * 256 + k0 + tx * 2 + jj] = acc[i][jj];
}

__global__ __launch_bounds__(256) void jsd_reduce_k(const float* __restrict__ Cpart,
                                                    float* __restrict__ C)
{
    int i = blockIdx.x * 256 + threadIdx.x;
    float s = 0.f;
    #pragma unroll
    for (int sl = 0; sl < 8; ++sl) s += Cpart[(size_t)sl * 65536 + i];
    C[i] = s;
}

// ---------------- per-k row/col sums of C ----------------
__global__ __launch_bounds__(256) void rc_k(const float* __restrict__ C,
                                            float* __restrict__ cmv,
                                            float* __restrict__ rmv)
{
    __shared__ float red[256];
    const int k = blockIdx.x, j = threadIdx.x;
    float cm = C[(size_t)j * 256 + k];
    float rm = C[(size_t)k * 256 + j];
    cm = bsum(cm, red);
    rm = bsum(rm, red);
    if (j == 0) { cmv[k] = cm; rmv[k] = rm; }
}

// ---------------- jm -> standardize -> softmax -> w ----------------
__global__ __launch_bounds__(256) void jmw_k(const float* __restrict__ cmv,
                                             const float* __restrict__ rmv,
                                             const float* __restrict__ ent,
                                             float* __restrict__ w)
{
    __shared__ float red[256];
    const int k = threadIdx.x;
    float e = ent[k];
    float esum = bsum(e, red);

    float jm = 0.5f * (esum * (1.f / 256.f) + e - (cmv[k] + rmv[k]) * (1.f / 256.f));

    float mean = bsum(jm, red) * (1.f / 256.f);
    float d = jm - mean;
    float var = bsum(d * d, red) * (1.f / 255.f);
    float v = d / (sqrtf(var) + 1e-6f);

    float mx = bmax(v, red);
    float ex = __expf(v - mx);
    float s = bsum(ex, red);
    w[k] = ex / s;
}

// ---------------- Hw[n,j] = H[n,j]*w[j] ----------------
__global__ __launch_bounds__(256) void hw_k(const float* __restrict__ H,
                                            const float* __restrict__ w,
                                            float* __restrict__ Hw)
{
    int i = blockIdx.x * 256 + threadIdx.x;
    Hw[i] = H[i] * w[i & 255];
}

__global__ __launch_bounds__(256) void copy_k(const float* __restrict__ src,
                                              float* __restrict__ dst)
{
    int i = blockIdx.x * 256 + threadIdx.x;
    dst[i] = src[i];
}

// ---------------- launch ----------------
extern "C" void kernel_launch(void* const* d_in, const int* in_sizes, int n_in,
                              void* d_out, int out_size, void* d_ws, size_t ws_size,
                              hipStream_t stream) {
    const float* x_time = (const float*)d_in[0];
    const float* x_news = (const float*)d_in[1];
    const float* f1w = (const float*)d_in[34];
    const float* f1b = (const float*)d_in[35];
    const float* f2w = (const float*)d_in[36];
    const float* f2b = (const float*)d_in[37];
    const float* theta_t = (const float*)d_in[38];
    const float* theta_n = (const float*)d_in[39];
    float* out = (float*)d_out;

    float* ws = (float*)d_ws;
    // pair-scratch region [0, 3145728 floats): qk (bf16) + S (bf16); recycled later.
    short* s_qk = (short*)ws;                   // 4 x 524288 halves (q0,q1,k0,k1)
    short* s_S  = s_qk + 4 * 524288;            // 4 x 1048576 halves (tag,head)
    float* z2b   = ws;                          // 4 x 262144 fp32   (after pair loop)
    float* Cpartf = ws + 1048576;               // 4 x 262144 fp32 (fusion split-K)
    float* Cpart  = ws + 1048576;               // 8 x 65536 fp32 (jsd, sequential alias)
    float* Pbuf   = ws + 1048576;               // 2 x 524288 fp32 (final, after jsd)
    float* Gpart  = ws + 2097152;               // 4 x 131072 fp32
    float* Gbuf   = ws + 2621440;               // 2 x 131072 fp32
    // persistent regions:
    short* s_a   = (short*)(ws + 3145728);      // 4 x 1048576 halves (attn matrices)
    short* s_z1  = (short*)(ws + 5242880);      // 4 x 262144 halves (z1; slot0 reused as z1f)
    short* s_Hc  = (short*)(ws + 5767168);      // 1024 x 1024 halves (Hcat)
    float* Hbuf  = ws + 6291456;                // 262144
    float* Hw    = ws + 6553600;                // 262144
    float* Cb    = ws + 6815744;                // 65536
    float* entv  = ws + 6881280;                // 256
    float* cmv   = entv + 256;
    float* rmv   = cmv + 256;
    float* wv    = rmv + 256;

    const float* qsrc[4]  = {x_time, x_news, x_time, x_news};
    const float* kvsrc[4] = {x_time, x_news, x_news, x_time};
    const int    base[4]  = {2, 10, 18, 26};

    Batch8 bp{};

    // ======== attention pairs: projections -> scores -> softmax+mean ========
    for (int p = 0; p < 2; ++p) {
        int tg0 = 2 * p, tg1 = 2 * p + 1;
        // projections: {q_tg0, q_tg1, k_tg0, k_tg1}, C bf16 [1024x512]
        bp.A[0] = qsrc[tg0];  bp.B[0] = d_in[base[tg0] + 0]; bp.bias[0] = (const float*)d_in[base[tg0] + 2];
        bp.A[1] = qsrc[tg1];  bp.B[1] = d_in[base[tg1] + 0]; bp.bias[1] = (const float*)d_in[base[tg1] + 2];
        bp.A[2] = kvsrc[tg0]; bp.B[2] = d_in[base[tg0] + 1]; bp.bias[2] = (const float*)d_in[base[tg0] + 3];
        bp.A[3] = kvsrc[tg1]; bp.B[3] = d_in[base[tg1] + 1]; bp.bias[3] = (const float*)d_in[base[tg1] + 3];
        for (int i = 0; i < 4; ++i) bp.C[i] = s_qk + (size_t)i * 524288;
        gemm_b_k<float, float, short, false, false, 1>
            <<<dim3(8, 16, 4), 256, 0, stream>>>(bp, 512, 512, 512, 512, 1.f);

        // scores: {(tg0,h0),(tg0,h1),(tg1,h0),(tg1,h1)}, S bf16 [1024x1024], scale 1/16
        for (int i = 0; i < 4; ++i) {
            int tg = i >> 1, h = i & 1;
            bp.A[i] = s_qk + (size_t)tg * 524288 + h * 256;             // q
            bp.B[i] = s_qk + (size_t)(2 + tg) * 524288 + h * 256;       // k
            bp.bias[i] = nullptr;
            bp.C[i] = s_S + ((size_t)i << 20);
        }
        gemm_b_k<short, short, short, false, false, 0>
            <<<dim3(16, 16, 4), 256, 0, stream>>>(bp, 512, 512, 1024, 256, 0.0625f);

        // softmax + head mean -> a (bf16)
        softmax_mean_b<<<2048, 256, 0, stream>>>(s_S, s_a + ((size_t)tg0 << 20));
    }

    // ======== incidence MLPs (batched over 4 tags) ========
    for (int tg = 0; tg < 4; ++tg) {
        bp.A[tg] = s_a + ((size_t)tg << 20);
        bp.B[tg] = d_in[base[tg] + 4];                       // h1w fp32 [256x1024]
        bp.bias[tg] = (const float*)d_in[base[tg] + 5];
        bp.C[tg] = s_z1 + (size_t)tg * 262144;
    }
    gemm_b_k<short, float, short, false, false, 2>
        <<<dim3(4, 16, 4), 256, 0, stream>>>(bp, 1024, 1024, 256, 1024, 1.f);

    for (int tg = 0; tg < 4; ++tg) {
        bp.A[tg] = s_z1 + (size_t)tg * 262144;
        bp.B[tg] = d_in[base[tg] + 6];                       // h2w fp32 [256x256]
        bp.bias[tg] = (const float*)d_in[base[tg] + 7];
        bp.C[tg] = z2b + (size_t)tg * 262144;
    }
    gemm_b_k<short, float, float, false, false, 1>
        <<<dim3(4, 16, 4), 256, 0, stream>>>(bp, 256, 256, 256, 256, 1.f);

    // norm_softmax over 4 tags -> Hcat (bf16, [1024 x 1024])
    norm_softmax_b<short><<<dim3(256, 4), 256, 0, stream>>>(z2b, 262144, s_Hc, 1024, 256);

    // ======== fusion MLP (split-K z=4) + norm_softmax -> Hbuf ========
    for (int z = 0; z < 4; ++z) {
        bp.A[z] = s_Hc + z * 256;
        bp.B[z] = f1w + z * 256;
        bp.bias[z] = nullptr;
        bp.C[z] = Cpartf + (size_t)z * 262144;
    }
    gemm_b_k<short, float, float, false, false, 0>
        <<<dim3(4, 16, 4), 256, 0, stream>>>(bp, 1024, 1024, 256, 256, 1.f);
    freduce_k<<<1024, 256, 0, stream>>>(Cpartf, f1b, s_z1);   // z1f = z1 slot0

    bp.A[0] = s_z1; bp.B[0] = f2w; bp.bias[0] = f2b; bp.C[0] = z2b;
    gemm_b_k<short, float, float, false, false, 1>
        <<<dim3(4, 16, 1), 256, 0, stream>>>(bp, 256, 256, 256, 256, 1.f);
    norm_softmax_b<float><<<dim3(256, 1), 256, 0, stream>>>(z2b, 0, Hbuf, 256, 0);

    // ======== JSD -> w ========
    ent_k<<<256, 256, 0, stream>>>(Hbuf, entv);
    jsd_part_k<<<dim3(8, 8, 8), 256, 0, stream>>>(Hbuf, Cpart);
    jsd_reduce_k<<<256, 256, 0, stream>>>(Cpart, Cb);
    rc_k<<<256, 256, 0, stream>>>(Cb, cmv, rmv);
    jmw_k<<<1, 256, 0, stream>>>(cmv, rmv, entv, wv);
    hw_k<<<1024, 256, 0, stream>>>(Hbuf, wv, Hw);

    // ======== finals: G = H^T X (split-K), P = Hw G, out = x + elu(P theta) ====
    const float* xc[2] = {x_time, x_news};
    const float* th[2] = {theta_t, theta_n};
    for (int i = 0; i < 4; ++i) {                 // i = chain*2 + slab
        int chain = i >> 1, slab = i & 1;
        bp.A[i] = Hbuf + (size_t)slab * 512 * 256;
        bp.B[i] = xc[chain] + (size_t)slab * 512 * 512;
        bp.bias[i] = nullptr;
        bp.C[i] = Gpart + (size_t)i * 131072;
    }
    gemm_b_k<float, float, float, true, true, 0>
        <<<dim3(8, 4, 4), 256, 0, stream>>>(bp, 256, 512, 512, 512, 1.f);
    g_reduce_k<<<dim3(512, 2), 256, 0, stream>>>(Gpart, Gbuf);

    for (int c = 0; c < 2; ++c) {
        bp.A[c] = Hw;
        bp.B[c] = Gbuf + (size_t)c * 131072;
        bp.bias[c] = nullptr;
        bp.C[c] = Pbuf + (size_t)c * 524288;
    }
    gemm_b_k<float, float, float, false, true, 0>
        <<<dim3(8, 16, 2), 256, 0, stream>>>(bp, 256, 512, 512, 256, 1.f);

    for (int c = 0; c < 2; ++c) {
        bp.A[c] = Pbuf + (size_t)c * 524288;
        bp.B[c] = th[c];
        bp.bias[c] = nullptr;
        bp.add[c] = xc[c];
        bp.C[c] = out + (size_t)c * 524288;
    }
    gemm_b_k<float, float, float, false, true, 3>
        <<<dim3(8, 16, 2), 256, 0, stream>>>(bp, 512, 512, 512, 512, 1.f);

    // H output
    copy_k<<<1024, 256, 0, stream>>>(Hbuf, out + 1048576);
}

// Round 5
// 246.714 us; speedup vs baseline: 5.9634x; 1.1093x over previous
//
#include <hip/hip_runtime.h>
#include <hip/hip_bf16.h>
#include <math.h>

typedef __attribute__((ext_vector_type(8))) short bf16x8;
typedef __attribute__((ext_vector_type(8))) short short8;
typedef __attribute__((ext_vector_type(4))) float f32x4;

__device__ __forceinline__ short f2bf(float f) {
    unsigned u = __float_as_uint(f);
    u += 0x7fffu + ((u >> 16) & 1u);
    return (short)(u >> 16);
}
__device__ __forceinline__ float bf2f(short s) {
    return __uint_as_float(((unsigned)(unsigned short)s) << 16);
}

// ---------------- block reduction helpers (blockDim.x == 256) ----------------
__device__ __forceinline__ float bsum(float v, float* red) {
    int t = threadIdx.x;
    red[t] = v; __syncthreads();
    #pragma unroll
    for (int s = 128; s >= 1; s >>= 1) {
        if (t < s) red[t] += red[t + s];
        __syncthreads();
    }
    float r = red[0]; __syncthreads();
    return r;
}

__device__ __forceinline__ float bmax(float v, float* red) {
    int t = threadIdx.x;
    red[t] = v; __syncthreads();
    #pragma unroll
    for (int s = 128; s >= 1; s >>= 1) {
        if (t < s) red[t] = fmaxf(red[t], red[t + s]);
        __syncthreads();
    }
    float r = red[0]; __syncthreads();
    return r;
}

// ---------------- batched MFMA bf16 GEMM ----------------
// Per batch z: C[m,n] = scale * sum_k Aelem(m,k)*Belem(k,n)  (+epilogue)
// TA/TB/TC: float or short(bf16 bits). TRA/TRB: operand stored K-major (fp32 only).
// EPI: 0 none, 1 +bias, 2 +bias+relu, 3 out = add + elu(v)
// WS: multiply A(m,k) by wsc[k] during staging (fp32 non-TRA path only).
// Tile 64x64, BK=32, 4 waves each 32x32 via mfma_f32_16x16x32_bf16.
struct Batch8 {
    const void* A[8];
    const void* B[8];
    const float* bias[8];
    const float* add[8];
    void* C[8];
};

template<typename TA, typename TB, typename TC, bool TRA, bool TRB, int EPI, bool WS = false>
__global__ __launch_bounds__(256) void gemm_b_k(Batch8 bp, int lda, int ldb, int ldc,
                                                int K, float scale,
                                                const float* __restrict__ wsc = nullptr)
{
    __shared__ __align__(16) short As[64 * 40];
    __shared__ __align__(16) short Bs[64 * 40];
    const int t = threadIdx.x;
    const int lane = t & 63;
    const int w = t >> 6, wm = w >> 1, wn = w & 1;
    const int bm = blockIdx.y * 64, bn = blockIdx.x * 64;
    const int l15 = lane & 15, l4 = lane >> 4;
    const TA* __restrict__ A = (const TA*)bp.A[blockIdx.z];
    const TB* __restrict__ B = (const TB*)bp.B[blockIdx.z];

    f32x4 acc[2][2];
    #pragma unroll
    for (int i = 0; i < 2; ++i)
        #pragma unroll
        for (int j = 0; j < 2; ++j)
            #pragma unroll
            for (int r = 0; r < 4; ++r) acc[i][j][r] = 0.f;

    for (int k0 = 0; k0 < K; k0 += 32) {
        // ---- stage A ----
        if constexpr (!TRA) {
            if constexpr (sizeof(TA) == 4) {
                #pragma unroll
                for (int p = 0; p < 2; ++p) {
                    int row = (t >> 3) + p * 32;
                    int c4 = (t & 7) * 4;
                    float4 v = *reinterpret_cast<const float4*>(
                        A + (size_t)(bm + row) * lda + k0 + c4);
                    if constexpr (WS) {
                        v.x *= wsc[k0 + c4 + 0]; v.y *= wsc[k0 + c4 + 1];
                        v.z *= wsc[k0 + c4 + 2]; v.w *= wsc[k0 + c4 + 3];
                    }
                    short4 s4 = make_short4(f2bf(v.x), f2bf(v.y), f2bf(v.z), f2bf(v.w));
                    *reinterpret_cast<short4*>(&As[row * 40 + c4]) = s4;
                }
            } else {
                int row = t >> 2, c8 = (t & 3) * 8;
                short8 v = *reinterpret_cast<const short8*>(
                    A + (size_t)(bm + row) * lda + k0 + c8);
                *reinterpret_cast<short8*>(&As[row * 40 + c8]) = v;
            }
        } else {
            #pragma unroll
            for (int p = 0; p < 2; ++p) {
                int kk = (t >> 4) + p * 16;
                int m4 = (t & 15) * 4;
                const float4 v = *reinterpret_cast<const float4*>(
                    (const float*)A + (size_t)(k0 + kk) * lda + bm + m4);
                As[(m4 + 0) * 40 + kk] = f2bf(v.x);
                As[(m4 + 1) * 40 + kk] = f2bf(v.y);
                As[(m4 + 2) * 40 + kk] = f2bf(v.z);
                As[(m4 + 3) * 40 + kk] = f2bf(v.w);
            }
        }
        // ---- stage B ----
        if constexpr (!TRB) {
            if constexpr (sizeof(TB) == 4) {
                #pragma unroll
                for (int p = 0; p < 2; ++p) {
                    int row = (t >> 3) + p * 32;
                    int c4 = (t & 7) * 4;
                    const float4 v = *reinterpret_cast<const float4*>(
                        B + (size_t)(bn + row) * ldb + k0 + c4);
                    short4 s4 = make_short4(f2bf(v.x), f2bf(v.y), f2bf(v.z), f2bf(v.w));
                    *reinterpret_cast<short4*>(&Bs[row * 40 + c4]) = s4;
                }
            } else {
                int row = t >> 2, c8 = (t & 3) * 8;
                short8 v = *reinterpret_cast<const short8*>(
                    B + (size_t)(bn + row) * ldb + k0 + c8);
                *reinterpret_cast<short8*>(&Bs[row * 40 + c8]) = v;
            }
        } else {
            #pragma unroll
            for (int p = 0; p < 2; ++p) {
                int kk = (t >> 4) + p * 16;
                int n4 = (t & 15) * 4;
                const float4 v = *reinterpret_cast<const float4*>(
                    (const float*)B + (size_t)(k0 + kk) * ldb + bn + n4);
                Bs[(n4 + 0) * 40 + kk] = f2bf(v.x);
                Bs[(n4 + 1) * 40 + kk] = f2bf(v.y);
                Bs[(n4 + 2) * 40 + kk] = f2bf(v.z);
                Bs[(n4 + 3) * 40 + kk] = f2bf(v.w);
            }
        }
        __syncthreads();

        const bf16x8* Ap = reinterpret_cast<const bf16x8*>(As);
        const bf16x8* Bp = reinterpret_cast<const bf16x8*>(Bs);
        bf16x8 af[2], bfr[2];
        #pragma unroll
        for (int mi = 0; mi < 2; ++mi)
            af[mi] = Ap[(wm * 32 + mi * 16 + l15) * 5 + l4];
        #pragma unroll
        for (int ni = 0; ni < 2; ++ni)
            bfr[ni] = Bp[(wn * 32 + ni * 16 + l15) * 5 + l4];
        #pragma unroll
        for (int mi = 0; mi < 2; ++mi)
            #pragma unroll
            for (int ni = 0; ni < 2; ++ni)
                acc[mi][ni] = __builtin_amdgcn_mfma_f32_16x16x32_bf16(
                    af[mi], bfr[ni], acc[mi][ni], 0, 0, 0);
        __syncthreads();
    }

    const float* bias = bp.bias[blockIdx.z];
    const float* add = bp.add[blockIdx.z];
    TC* __restrict__ C = (TC*)bp.C[blockIdx.z];
    #pragma unroll
    for (int mi = 0; mi < 2; ++mi) {
        #pragma unroll
        for (int ni = 0; ni < 2; ++ni) {
            int col = bn + wn * 32 + ni * 16 + l15;
            #pragma unroll
            for (int r = 0; r < 4; ++r) {
                int row = bm + wm * 32 + mi * 16 + l4 * 4 + r;
                float v = acc[mi][ni][r] * scale;
                if (EPI == 1) v += bias[col];
                if (EPI == 2) v = fmaxf(v + bias[col], 0.f);
                if (EPI == 3) {
                    float e = v > 0.f ? v : (__expf(v) - 1.f);
                    v = add[(size_t)row * ldc + col] + e;
                }
                if constexpr (sizeof(TC) == 4) C[(size_t)row * ldc + col] = v;
                else C[(size_t)row * ldc + col] = f2bf(v);
            }
        }
    }
}

// ---------------- attention softmax + head-mean (bf16 in/out), all 4 tags ----
// grid.x = 4096: tag = x>>10, row = x&1023. S layout: [tag*2+head][1024][1024] bf16.
__global__ __launch_bounds__(256) void softmax_mean_b(const short* __restrict__ S,
                                                      short* __restrict__ a)
{
    __shared__ float red[256];
    const int g = blockIdx.x, t = threadIdx.x;
    const int tag = g >> 10, row = g & 1023;
    const short* s0 = S + ((size_t)(tag * 2 + 0) << 20) + (size_t)row * 1024 + t * 4;
    const short* s1 = S + ((size_t)(tag * 2 + 1) << 20) + (size_t)row * 1024 + t * 4;

    short4 r0 = *reinterpret_cast<const short4*>(s0);
    short4 r1 = *reinterpret_cast<const short4*>(s1);
    float v0[4] = {bf2f(r0.x), bf2f(r0.y), bf2f(r0.z), bf2f(r0.w)};
    float v1[4] = {bf2f(r1.x), bf2f(r1.y), bf2f(r1.z), bf2f(r1.w)};

    float m0 = fmaxf(fmaxf(v0[0], v0[1]), fmaxf(v0[2], v0[3]));
    float m1 = fmaxf(fmaxf(v1[0], v1[1]), fmaxf(v1[2], v1[3]));
    m0 = bmax(m0, red);
    m1 = bmax(m1, red);

    float e0[4], e1[4], sum0 = 0.f, sum1 = 0.f;
    #pragma unroll
    for (int j = 0; j < 4; ++j) {
        e0[j] = __expf(v0[j] - m0); sum0 += e0[j];
        e1[j] = __expf(v1[j] - m1); sum1 += e1[j];
    }
    sum0 = bsum(sum0, red);
    sum1 = bsum(sum1, red);
    float i0 = 0.5f / sum0, i1 = 0.5f / sum1;

    short4 o;
    o.x = f2bf(e0[0] * i0 + e1[0] * i1);
    o.y = f2bf(e0[1] * i0 + e1[1] * i1);
    o.z = f2bf(e0[2] * i0 + e1[2] * i1);
    o.w = f2bf(e0[3] * i0 + e1[3] * i1);
    *reinterpret_cast<short4*>(a + ((size_t)tag << 20) + (size_t)row * 1024 + t * 4) = o;
}

// ---------------- MLP1 split-K reduce: z1[tag] = bf16(relu(p0+p1+b)) --------
struct Ptr4 { const float* p[4]; };
__global__ __launch_bounds__(256) void mlp1_red_k(const float* __restrict__ zpart,
                                                  Ptr4 bias,
                                                  short* __restrict__ z1)
{
    int i = blockIdx.x * 256 + threadIdx.x;          // over 4*262144
    int tag = i >> 18, idx = i & 262143, col = i & 255;
    float s = bias.p[tag][col]
            + zpart[(size_t)(tag * 2 + 0) * 262144 + idx]
            + zpart[(size_t)(tag * 2 + 1) * 262144 + idx];
    z1[i] = f2bf(fmaxf(s, 0.f));
}

// ---------------- column standardize (ddof=1) + column softmax, batched ------
template<typename TOUT>
__global__ __launch_bounds__(256) void norm_softmax_b(const float* __restrict__ Zbase,
                                                      int zstride,
                                                      TOUT* __restrict__ Hout, int ldh,
                                                      int joffmul,
                                                      float* __restrict__ out2)
{
    __shared__ float red[256];
    const int j = blockIdx.x, t = threadIdx.x;
    const float* Z = Zbase + (size_t)blockIdx.y * zstride;
    const int joff = blockIdx.y * joffmul;

    float x[4];
    #pragma unroll
    for (int i = 0; i < 4; ++i) x[i] = Z[(size_t)(t + i * 256) * 256 + j];

    float s = x[0] + x[1] + x[2] + x[3];
    float mean = bsum(s, red) * (1.f / 1024.f);

    float ss = 0.f;
    #pragma unroll
    for (int i = 0; i < 4; ++i) { float d = x[i] - mean; ss += d * d; }
    float var = bsum(ss, red) * (1.f / 1023.f);
    float inv = 1.f / (sqrtf(var) + 1e-6f);

    float v[4];
    float mx = -3.4e38f;
    #pragma unroll
    for (int i = 0; i < 4; ++i) { v[i] = (x[i] - mean) * inv; mx = fmaxf(mx, v[i]); }
    mx = bmax(mx, red);

    float e[4], es = 0.f;
    #pragma unroll
    for (int i = 0; i < 4; ++i) { e[i] = __expf(v[i] - mx); es += e[i]; }
    es = bsum(es, red);
    float invs = 1.f / es;

    #pragma unroll
    for (int i = 0; i < 4; ++i) {
        float o = e[i] * invs;
        if constexpr (sizeof(TOUT) == 4)
            Hout[(size_t)(t + i * 256) * ldh + joff + j] = o;
        else
            Hout[(size_t)(t + i * 256) * ldh + joff + j] = f2bf(o);
        if (out2) out2[(size_t)(t + i * 256) * 256 + joff + j] = o;
    }
}

// ---------------- fusion split-K reduce: z1f = bf16(relu(sum_s + b)) ---------
__global__ __launch_bounds__(256) void freduce_k(const float* __restrict__ Cpartf,
                                                 const float* __restrict__ b,
                                                 short* __restrict__ z1f)
{
    int i = blockIdx.x * 256 + threadIdx.x;
    float s = b[i & 255];
    #pragma unroll
    for (int z = 0; z < 4; ++z) s += Cpartf[(size_t)z * 262144 + i];
    z1f[i] = f2bf(fmaxf(s, 0.f));
}

// ---------------- G split-K reduce ----------------
__global__ __launch_bounds__(256) void g_reduce_k(const float* __restrict__ Gpart,
                                                  float* __restrict__ G)
{
    int chain = blockIdx.y;
    int i = blockIdx.x * 256 + threadIdx.x;
    G[(size_t)chain * 131072 + i] =
        Gpart[(size_t)(chain * 2 + 0) * 131072 + i] +
        Gpart[(size_t)(chain * 2 + 1) * 131072 + i];
}

// ---------------- ent[j] = sum_n H[n,j]*log(H[n,j]) ----------------
__global__ __launch_bounds__(256) void ent_k(const float* __restrict__ H,
                                             float* __restrict__ ent)
{
    __shared__ float red[256];
    const int j = blockIdx.x, t = threadIdx.x;
    float s = 0.f;
    #pragma unroll
    for (int i = 0; i < 4; ++i) {
        float h = H[(size_t)(t + i * 256) * 256 + j];
        s += h * __logf(h);
    }
    s = bsum(s, red);
    if (t == 0) ent[j] = s;
}

// ---------------- Cpart[s][j][k] = sum_{n in slab s(64)} H[n,j]*log(0.5*(H[n,j]+H[n,k]))
__global__ __launch_bounds__(256) void jsd_part_k(const float* __restrict__ H,
                                                  float* __restrict__ Cpart)
{
    __shared__ float hj[8][33];
    __shared__ float hk[8][33];
    const int t = threadIdx.x;
    const int tx = t & 15, ty = t >> 4;
    const int j0 = blockIdx.y * 32, k0 = blockIdx.x * 32;
    const int nbase = blockIdx.z * 64;

    float acc[2][2] = {};

    for (int c = 0; c < 8; ++c) {
        int n0 = nbase + c * 8;
        int nl = t >> 5, cc = t & 31;
        hj[nl][cc] = H[(size_t)(n0 + nl) * 256 + j0 + cc];
        hk[nl][cc] = H[(size_t)(n0 + nl) * 256 + k0 + cc];
        __syncthreads();
        #pragma unroll
        for (int nn = 0; nn < 8; ++nn) {
            float a0 = hj[nn][ty * 2], a1 = hj[nn][ty * 2 + 1];
            float b0 = hk[nn][tx * 2], b1 = hk[nn][tx * 2 + 1];
            acc[0][0] += a0 * __logf(0.5f * (a0 + b0));
            acc[0][1] += a0 * __logf(0.5f * (a0 + b1));
            acc[1][0] += a1 * __logf(0.5f * (a1 + b0));
            acc[1][1] += a1 * __logf(0.5f * (a1 + b1));
        }
        __syncthreads();
    }
    float* Cp = Cpart + (size_t)blockIdx.z * 65536;
    #pragma unroll
    for (int i = 0; i < 2; ++i)
        #pragma unroll
        for (int jj = 0; jj < 2; ++jj)
            Cp[(size_t)(j0 + ty * 2 + i) * 256 + k0 + tx * 2 + jj] = acc[i][jj];
}

// ---------------- per-k row/col sums over 16 slabs ----------------
__global__ __launch_bounds__(256) void rc_k(const float* __restrict__ Cpart,
                                            float* __restrict__ cmv,
                                            float* __restrict__ rmv)
{
    __shared__ float red[256];
    const int k = blockIdx.x, j = threadIdx.x;
    float cm = 0.f, rm = 0.f;
    #pragma unroll
    for (int s = 0; s < 16; ++s) {
        cm += Cpart[(size_t)s * 65536 + (size_t)j * 256 + k];
        rm += Cpart[(size_t)s * 65536 + (size_t)k * 256 + j];
    }
    cm = bsum(cm, red);
    rm = bsum(rm, red);
    if (j == 0) { cmv[k] = cm; rmv[k] = rm; }
}

// ---------------- jm -> standardize -> softmax -> w ----------------
__global__ __launch_bounds__(256) void jmw_k(const float* __restrict__ cmv,
                                             const float* __restrict__ rmv,
                                             const float* __restrict__ ent,
                                             float* __restrict__ w)
{
    __shared__ float red[256];
    const int k = threadIdx.x;
    float e = ent[k];
    float esum = bsum(e, red);

    float jm = 0.5f * (esum * (1.f / 256.f) + e - (cmv[k] + rmv[k]) * (1.f / 256.f));

    float mean = bsum(jm, red) * (1.f / 256.f);
    float d = jm - mean;
    float var = bsum(d * d, red) * (1.f / 255.f);
    float v = d / (sqrtf(var) + 1e-6f);

    float mx = bmax(v, red);
    float ex = __expf(v - mx);
    float s = bsum(ex, red);
    w[k] = ex / s;
}

// ---------------- launch ----------------
extern "C" void kernel_launch(void* const* d_in, const int* in_sizes, int n_in,
                              void* d_out, int out_size, void* d_ws, size_t ws_size,
                              hipStream_t stream) {
    const float* x_time = (const float*)d_in[0];
    const float* x_news = (const float*)d_in[1];
    const float* f1w = (const float*)d_in[34];
    const float* f1b = (const float*)d_in[35];
    const float* f2w = (const float*)d_in[36];
    const float* f2b = (const float*)d_in[37];
    const float* theta_t = (const float*)d_in[38];
    const float* theta_n = (const float*)d_in[39];
    float* out = (float*)d_out;

    float* ws = (float*)d_ws;
    // region 0 [0 .. 2,097,152 fl): qk (8x524288 halves) -> a (4x1M halves) -> Hc
    short* s_qk = (short*)ws;
    short* s_a  = (short*)ws;                    // aliases qk (qk dead after scores)
    short* s_Hc = (short*)ws;                    // aliases a  (a dead after MLP1)
    // region 1 [2,097,152 .. 6,291,456 fl): S (8x1M halves) -> everything later
    short* s_S    = (short*)(ws + 2097152);      // 8 x 1048576 halves (16 MB)
    float* zpart  = ws + 2097152;                // 8 x 262144 fl (MLP1 split-K)
    short* s_z1   = (short*)(ws + 4194304);      // 4 x 262144 halves
    float* z2b    = ws + 4718592;                // 4 x 262144 fl
    float* Cpartf = ws + 2097152;                // 4 x 262144 fl (fusion, zpart dead)
    short* z1f    = s_z1;                        // slot 0 (z1 dead after MLP2)
    float* z2f    = z2b;                         // slot 0 (z2b dead after Hc)
    float* Cpart  = ws + 2097152;                // 16 x 65536 fl (jsd)
    float* entv   = ws + 3145728;                // smalls
    float* cmv    = entv + 256;
    float* rmv    = cmv + 256;
    float* wv     = rmv + 256;
    float* Gpart  = ws + 3407872;                // 4 x 131072 fl
    float* Gbuf   = ws + 3932160;                // 2 x 131072 fl
    float* Pbuf   = ws + 4194304;                // 2 x 524288 fl (z1/z2b dead)
    // persistent:
    float* Hbuf   = ws + 6291456;                // 262144 fl  (peak 26.2 MB)

    const float* qsrc[4]  = {x_time, x_news, x_time, x_news};
    const float* kvsrc[4] = {x_time, x_news, x_news, x_time};
    const int    base[4]  = {2, 10, 18, 26};

    Batch8 bp{};

    // ======== projections: z=8 {q_t,q_n,q_tn,q_nt,k_t,k_n,k_tn,k_nt} ========
    for (int tg = 0; tg < 4; ++tg) {
        bp.A[tg] = qsrc[tg];      bp.B[tg] = d_in[base[tg] + 0];
        bp.bias[tg] = (const float*)d_in[base[tg] + 2];
        bp.C[tg] = s_qk + (size_t)tg * 524288;
        bp.A[4 + tg] = kvsrc[tg]; bp.B[4 + tg] = d_in[base[tg] + 1];
        bp.bias[4 + tg] = (const float*)d_in[base[tg] + 3];
        bp.C[4 + tg] = s_qk + (size_t)(4 + tg) * 524288;
    }
    gemm_b_k<float, float, short, false, false, 1>
        <<<dim3(8, 16, 8), 256, 0, stream>>>(bp, 512, 512, 512, 512, 1.f);

    // ======== scores: z=8 (tag,head), S bf16, scale 1/16 ========
    for (int i = 0; i < 8; ++i) {
        int tg = i >> 1, h = i & 1;
        bp.A[i] = s_qk + (size_t)tg * 524288 + h * 256;
        bp.B[i] = s_qk + (size_t)(4 + tg) * 524288 + h * 256;
        bp.bias[i] = nullptr;
        bp.C[i] = s_S + ((size_t)i << 20);
    }
    gemm_b_k<short, short, short, false, false, 0>
        <<<dim3(16, 16, 8), 256, 0, stream>>>(bp, 512, 512, 1024, 256, 0.0625f);

    // ======== softmax + head mean -> a (bf16), all tags ========
    softmax_mean_b<<<4096, 256, 0, stream>>>(s_S, s_a);

    // ======== incidence MLP1: split-K z=8 (tag,half) ========
    for (int i = 0; i < 8; ++i) {
        int tg = i >> 1, hf = i & 1;
        bp.A[i] = s_a + ((size_t)tg << 20) + hf * 512;
        bp.B[i] = (const float*)d_in[base[tg] + 4] + hf * 512;
        bp.bias[i] = nullptr;
        bp.C[i] = zpart + (size_t)i * 262144;
    }
    gemm_b_k<short, float, float, false, false, 0>
        <<<dim3(4, 16, 8), 256, 0, stream>>>(bp, 1024, 1024, 256, 512, 1.f);
    Ptr4 b1{{(const float*)d_in[base[0] + 5], (const float*)d_in[base[1] + 5],
             (const float*)d_in[base[2] + 5], (const float*)d_in[base[3] + 5]}};
    mlp1_red_k<<<4096, 256, 0, stream>>>(zpart, b1, s_z1);

    // ======== incidence MLP2 z=4 ========
    for (int tg = 0; tg < 4; ++tg) {
        bp.A[tg] = s_z1 + (size_t)tg * 262144;
        bp.B[tg] = d_in[base[tg] + 6];
        bp.bias[tg] = (const float*)d_in[base[tg] + 7];
        bp.C[tg] = z2b + (size_t)tg * 262144;
    }
    gemm_b_k<short, float, float, false, false, 1>
        <<<dim3(4, 16, 4), 256, 0, stream>>>(bp, 256, 256, 256, 256, 1.f);

    // norm_softmax over 4 tags -> Hcat (bf16)
    norm_softmax_b<short><<<dim3(256, 4), 256, 0, stream>>>(z2b, 262144, s_Hc, 1024, 256, nullptr);

    // ======== fusion MLP (split-K z=4) + norm_softmax -> Hbuf (+out H) ========
    for (int z = 0; z < 4; ++z) {
        bp.A[z] = s_Hc + z * 256;
        bp.B[z] = f1w + z * 256;
        bp.bias[z] = nullptr;
        bp.C[z] = Cpartf + (size_t)z * 262144;
    }
    gemm_b_k<short, float, float, false, false, 0>
        <<<dim3(4, 16, 4), 256, 0, stream>>>(bp, 1024, 1024, 256, 256, 1.f);
    freduce_k<<<1024, 256, 0, stream>>>(Cpartf, f1b, z1f);

    bp.A[0] = z1f; bp.B[0] = f2w; bp.bias[0] = f2b; bp.C[0] = z2f;
    gemm_b_k<short, float, float, false, false, 1>
        <<<dim3(4, 16, 1), 256, 0, stream>>>(bp, 256, 256, 256, 256, 1.f);
    norm_softmax_b<float><<<dim3(256, 1), 256, 0, stream>>>(z2f, 0, Hbuf, 256, 0,
                                                            out + 1048576);

    // ======== JSD -> w ========
    ent_k<<<256, 256, 0, stream>>>(Hbuf, entv);
    jsd_part_k<<<dim3(8, 8, 16), 256, 0, stream>>>(Hbuf, Cpart);
    rc_k<<<256, 256, 0, stream>>>(Cpart, cmv, rmv);
    jmw_k<<<1, 256, 0, stream>>>(cmv, rmv, entv, wv);

    // ======== finals: G = H^T X (split-K), P = (H*w) G, out = x + elu(P theta) ==
    const float* xc[2] = {x_time, x_news};
    const float* th[2] = {theta_t, theta_n};
    for (int i = 0; i < 4; ++i) {                 // i = chain*2 + slab
        int chain = i >> 1, slab = i & 1;
        bp.A[i] = Hbuf + (size_t)slab * 512 * 256;
        bp.B[i] = xc[chain] + (size_t)slab * 512 * 512;
        bp.bias[i] = nullptr;
        bp.C[i] = Gpart + (size_t)i * 131072;
    }
    gemm_b_k<float, float, float, true, true, 0>
        <<<dim3(8, 4, 4), 256, 0, stream>>>(bp, 256, 512, 512, 512, 1.f);
    g_reduce_k<<<dim3(512, 2), 256, 0, stream>>>(Gpart, Gbuf);

    for (int c = 0; c < 2; ++c) {
        bp.A[c] = Hbuf;                            // wscale applies w[k]
        bp.B[c] = Gbuf + (size_t)c * 131072;
        bp.bias[c] = nullptr;
        bp.C[c] = Pbuf + (size_t)c * 524288;
    }
    gemm_b_k<float, float, float, false, true, 0, true>
        <<<dim3(8, 16, 2), 256, 0, stream>>>(bp, 256, 512, 512, 256, 1.f, wv);

    for (int c = 0; c < 2; ++c) {
        bp.A[c] = Pbuf + (size_t)c * 524288;
        bp.B[c] = th[c];
        bp.bias[c] = nullptr;
        bp.add[c] = xc[c];
        bp.C[c] = out + (size_t)c * 524288;
    }
    gemm_b_k<float, float, float, false, true, 3>
        <<<dim3(8, 16, 2), 256, 0, stream>>>(bp, 512, 512, 512, 512, 1.f);
}

// Round 6
// 239.215 us; speedup vs baseline: 6.1503x; 1.0313x over previous
//
#include <hip/hip_runtime.h>
#include <hip/hip_bf16.h>
#include <math.h>

typedef __attribute__((ext_vector_type(8))) short bf16x8;
typedef __attribute__((ext_vector_type(8))) short short8;
typedef __attribute__((ext_vector_type(4))) float f32x4;

__device__ __forceinline__ short f2bf(float f) {
    unsigned u = __float_as_uint(f);
    u += 0x7fffu + ((u >> 16) & 1u);
    return (short)(u >> 16);
}
__device__ __forceinline__ float bf2f(short s) {
    return __uint_as_float(((unsigned)(unsigned short)s) << 16);
}

// ---------------- block reduction helpers (blockDim.x == 256) ----------------
__device__ __forceinline__ float bsum(float v, float* red) {
    int t = threadIdx.x;
    red[t] = v; __syncthreads();
    #pragma unroll
    for (int s = 128; s >= 1; s >>= 1) {
        if (t < s) red[t] += red[t + s];
        __syncthreads();
    }
    float r = red[0]; __syncthreads();
    return r;
}

__device__ __forceinline__ float bmax(float v, float* red) {
    int t = threadIdx.x;
    red[t] = v; __syncthreads();
    #pragma unroll
    for (int s = 128; s >= 1; s >>= 1) {
        if (t < s) red[t] = fmaxf(red[t], red[t + s]);
        __syncthreads();
    }
    float r = red[0]; __syncthreads();
    return r;
}

struct Batch8 {
    const void* A[8];
    const void* B[8];
    const float* bias[8];
    const float* add[8];
    void* C[8];
};

// ---------------- BIG 128x128 MFMA GEMM (proj / scores) ----------------
// A: M×K row-major (TA float->convert or short bf16). B: N×K row-major (B^T).
// C: bf16, ldc. EPI: 0 none, 1 +bias. 4 waves, each 64x64 (4x4 frags of 16x16).
template<typename TA, typename TB, int EPI>
__global__ __launch_bounds__(256) void gemm_big_k(Batch8 bp, int lda, int ldb, int ldc,
                                                  int K, float scale)
{
    __shared__ __align__(16) short As[128 * 40];
    __shared__ __align__(16) short Bs[128 * 40];
    const int t = threadIdx.x;
    const int lane = t & 63;
    const int w = t >> 6, wm = w >> 1, wn = w & 1;
    const int bm = blockIdx.y * 128, bn = blockIdx.x * 128;
    const int l15 = lane & 15, l4 = lane >> 4;
    const TA* __restrict__ A = (const TA*)bp.A[blockIdx.z];
    const TB* __restrict__ B = (const TB*)bp.B[blockIdx.z];

    f32x4 acc[4][4];
    #pragma unroll
    for (int i = 0; i < 4; ++i)
        #pragma unroll
        for (int j = 0; j < 4; ++j)
            #pragma unroll
            for (int r = 0; r < 4; ++r) acc[i][j][r] = 0.f;

    for (int k0 = 0; k0 < K; k0 += 32) {
        // ---- stage A [128 rows x 32 k] ----
        if constexpr (sizeof(TA) == 4) {
            #pragma unroll
            for (int p = 0; p < 4; ++p) {
                int row = (t >> 3) + p * 32;
                int c4 = (t & 7) * 4;
                const float4 v = *reinterpret_cast<const float4*>(
                    A + (size_t)(bm + row) * lda + k0 + c4);
                short4 s4 = make_short4(f2bf(v.x), f2bf(v.y), f2bf(v.z), f2bf(v.w));
                *reinterpret_cast<short4*>(&As[row * 40 + c4]) = s4;
            }
        } else {
            #pragma unroll
            for (int p = 0; p < 2; ++p) {
                int row = (t >> 2) + p * 64;
                int c8 = (t & 3) * 8;
                short8 v = *reinterpret_cast<const short8*>(
                    A + (size_t)(bm + row) * lda + k0 + c8);
                *reinterpret_cast<short8*>(&As[row * 40 + c8]) = v;
            }
        }
        // ---- stage B [128 rows x 32 k] ----
        if constexpr (sizeof(TB) == 4) {
            #pragma unroll
            for (int p = 0; p < 4; ++p) {
                int row = (t >> 3) + p * 32;
                int c4 = (t & 7) * 4;
                const float4 v = *reinterpret_cast<const float4*>(
                    B + (size_t)(bn + row) * ldb + k0 + c4);
                short4 s4 = make_short4(f2bf(v.x), f2bf(v.y), f2bf(v.z), f2bf(v.w));
                *reinterpret_cast<short4*>(&Bs[row * 40 + c4]) = s4;
            }
        } else {
            #pragma unroll
            for (int p = 0; p < 2; ++p) {
                int row = (t >> 2) + p * 64;
                int c8 = (t & 3) * 8;
                short8 v = *reinterpret_cast<const short8*>(
                    B + (size_t)(bn + row) * ldb + k0 + c8);
                *reinterpret_cast<short8*>(&Bs[row * 40 + c8]) = v;
            }
        }
        __syncthreads();

        const bf16x8* Ap = reinterpret_cast<const bf16x8*>(As);
        const bf16x8* Bp = reinterpret_cast<const bf16x8*>(Bs);
        bf16x8 af[4], bfr[4];
        #pragma unroll
        for (int mi = 0; mi < 4; ++mi)
            af[mi] = Ap[(wm * 64 + mi * 16 + l15) * 5 + l4];
        #pragma unroll
        for (int ni = 0; ni < 4; ++ni)
            bfr[ni] = Bp[(wn * 64 + ni * 16 + l15) * 5 + l4];
        #pragma unroll
        for (int mi = 0; mi < 4; ++mi)
            #pragma unroll
            for (int ni = 0; ni < 4; ++ni)
                acc[mi][ni] = __builtin_amdgcn_mfma_f32_16x16x32_bf16(
                    af[mi], bfr[ni], acc[mi][ni], 0, 0, 0);
        __syncthreads();
    }

    const float* bias = bp.bias[blockIdx.z];
    short* __restrict__ C = (short*)bp.C[blockIdx.z];
    #pragma unroll
    for (int mi = 0; mi < 4; ++mi) {
        #pragma unroll
        for (int ni = 0; ni < 4; ++ni) {
            int col = bn + wn * 64 + ni * 16 + l15;
            #pragma unroll
            for (int r = 0; r < 4; ++r) {
                int row = bm + wm * 64 + mi * 16 + l4 * 4 + r;
                float v = acc[mi][ni][r] * scale;
                if (EPI == 1) v += bias[col];
                C[(size_t)row * ldc + col] = f2bf(v);
            }
        }
    }
}

// ---------------- 64x64 batched MFMA GEMM (everything else) ----------------
// EPI: 0 none, 1 +bias, 2 +bias+relu, 3 out = add + elu(v)
// WS: multiply A(m,k) by wsc[k] during staging (fp32 non-TRA path only).
template<typename TA, typename TB, typename TC, bool TRA, bool TRB, int EPI, bool WS = false>
__global__ __launch_bounds__(256) void gemm_b_k(Batch8 bp, int lda, int ldb, int ldc,
                                                int K, float scale,
                                                const float* __restrict__ wsc = nullptr)
{
    __shared__ __align__(16) short As[64 * 40];
    __shared__ __align__(16) short Bs[64 * 40];
    const int t = threadIdx.x;
    const int lane = t & 63;
    const int w = t >> 6, wm = w >> 1, wn = w & 1;
    const int bm = blockIdx.y * 64, bn = blockIdx.x * 64;
    const int l15 = lane & 15, l4 = lane >> 4;
    const TA* __restrict__ A = (const TA*)bp.A[blockIdx.z];
    const TB* __restrict__ B = (const TB*)bp.B[blockIdx.z];

    f32x4 acc[2][2];
    #pragma unroll
    for (int i = 0; i < 2; ++i)
        #pragma unroll
        for (int j = 0; j < 2; ++j)
            #pragma unroll
            for (int r = 0; r < 4; ++r) acc[i][j][r] = 0.f;

    for (int k0 = 0; k0 < K; k0 += 32) {
        // ---- stage A ----
        if constexpr (!TRA) {
            if constexpr (sizeof(TA) == 4) {
                #pragma unroll
                for (int p = 0; p < 2; ++p) {
                    int row = (t >> 3) + p * 32;
                    int c4 = (t & 7) * 4;
                    float4 v = *reinterpret_cast<const float4*>(
                        A + (size_t)(bm + row) * lda + k0 + c4);
                    if constexpr (WS) {
                        v.x *= wsc[k0 + c4 + 0]; v.y *= wsc[k0 + c4 + 1];
                        v.z *= wsc[k0 + c4 + 2]; v.w *= wsc[k0 + c4 + 3];
                    }
                    short4 s4 = make_short4(f2bf(v.x), f2bf(v.y), f2bf(v.z), f2bf(v.w));
                    *reinterpret_cast<short4*>(&As[row * 40 + c4]) = s4;
                }
            } else {
                int row = t >> 2, c8 = (t & 3) * 8;
                short8 v = *reinterpret_cast<const short8*>(
                    A + (size_t)(bm + row) * lda + k0 + c8);
                *reinterpret_cast<short8*>(&As[row * 40 + c8]) = v;
            }
        } else {
            #pragma unroll
            for (int p = 0; p < 2; ++p) {
                int kk = (t >> 4) + p * 16;
                int m4 = (t & 15) * 4;
                const float4 v = *reinterpret_cast<const float4*>(
                    (const float*)A + (size_t)(k0 + kk) * lda + bm + m4);
                As[(m4 + 0) * 40 + kk] = f2bf(v.x);
                As[(m4 + 1) * 40 + kk] = f2bf(v.y);
                As[(m4 + 2) * 40 + kk] = f2bf(v.z);
                As[(m4 + 3) * 40 + kk] = f2bf(v.w);
            }
        }
        // ---- stage B ----
        if constexpr (!TRB) {
            if constexpr (sizeof(TB) == 4) {
                #pragma unroll
                for (int p = 0; p < 2; ++p) {
                    int row = (t >> 3) + p * 32;
                    int c4 = (t & 7) * 4;
                    const float4 v = *reinterpret_cast<const float4*>(
                        B + (size_t)(bn + row) * ldb + k0 + c4);
                    short4 s4 = make_short4(f2bf(v.x), f2bf(v.y), f2bf(v.z), f2bf(v.w));
                    *reinterpret_cast<short4*>(&Bs[row * 40 + c4]) = s4;
                }
            } else {
                int row = t >> 2, c8 = (t & 3) * 8;
                short8 v = *reinterpret_cast<const short8*>(
                    B + (size_t)(bn + row) * ldb + k0 + c8);
                *reinterpret_cast<short8*>(&Bs[row * 40 + c8]) = v;
            }
        } else {
            #pragma unroll
            for (int p = 0; p < 2; ++p) {
                int kk = (t >> 4) + p * 16;
                int n4 = (t & 15) * 4;
                const float4 v = *reinterpret_cast<const float4*>(
                    (const float*)B + (size_t)(k0 + kk) * ldb + bn + n4);
                Bs[(n4 + 0) * 40 + kk] = f2bf(v.x);
                Bs[(n4 + 1) * 40 + kk] = f2bf(v.y);
                Bs[(n4 + 2) * 40 + kk] = f2bf(v.z);
                Bs[(n4 + 3) * 40 + kk] = f2bf(v.w);
            }
        }
        __syncthreads();

        const bf16x8* Ap = reinterpret_cast<const bf16x8*>(As);
        const bf16x8* Bp = reinterpret_cast<const bf16x8*>(Bs);
        bf16x8 af[2], bfr[2];
        #pragma unroll
        for (int mi = 0; mi < 2; ++mi)
            af[mi] = Ap[(wm * 32 + mi * 16 + l15) * 5 + l4];
        #pragma unroll
        for (int ni = 0; ni < 2; ++ni)
            bfr[ni] = Bp[(wn * 32 + ni * 16 + l15) * 5 + l4];
        #pragma unroll
        for (int mi = 0; mi < 2; ++mi)
            #pragma unroll
            for (int ni = 0; ni < 2; ++ni)
                acc[mi][ni] = __builtin_amdgcn_mfma_f32_16x16x32_bf16(
                    af[mi], bfr[ni], acc[mi][ni], 0, 0, 0);
        __syncthreads();
    }

    const float* bias = bp.bias[blockIdx.z];
    const float* add = bp.add[blockIdx.z];
    TC* __restrict__ C = (TC*)bp.C[blockIdx.z];
    #pragma unroll
    for (int mi = 0; mi < 2; ++mi) {
        #pragma unroll
        for (int ni = 0; ni < 2; ++ni) {
            int col = bn + wn * 32 + ni * 16 + l15;
            #pragma unroll
            for (int r = 0; r < 4; ++r) {
                int row = bm + wm * 32 + mi * 16 + l4 * 4 + r;
                float v = acc[mi][ni][r] * scale;
                if (EPI == 1) v += bias[col];
                if (EPI == 2) v = fmaxf(v + bias[col], 0.f);
                if (EPI == 3) {
                    float e = v > 0.f ? v : (__expf(v) - 1.f);
                    v = add[(size_t)row * ldc + col] + e;
                }
                if constexpr (sizeof(TC) == 4) C[(size_t)row * ldc + col] = v;
                else C[(size_t)row * ldc + col] = f2bf(v);
            }
        }
    }
}

// ---------------- attention softmax + head-mean (bf16 in/out), all 4 tags ----
__global__ __launch_bounds__(256) void softmax_mean_b(const short* __restrict__ S,
                                                      short* __restrict__ a)
{
    __shared__ float red[256];
    const int g = blockIdx.x, t = threadIdx.x;
    const int tag = g >> 10, row = g & 1023;
    const short* s0 = S + ((size_t)(tag * 2 + 0) << 20) + (size_t)row * 1024 + t * 4;
    const short* s1 = S + ((size_t)(tag * 2 + 1) << 20) + (size_t)row * 1024 + t * 4;

    short4 r0 = *reinterpret_cast<const short4*>(s0);
    short4 r1 = *reinterpret_cast<const short4*>(s1);
    float v0[4] = {bf2f(r0.x), bf2f(r0.y), bf2f(r0.z), bf2f(r0.w)};
    float v1[4] = {bf2f(r1.x), bf2f(r1.y), bf2f(r1.z), bf2f(r1.w)};

    float m0 = fmaxf(fmaxf(v0[0], v0[1]), fmaxf(v0[2], v0[3]));
    float m1 = fmaxf(fmaxf(v1[0], v1[1]), fmaxf(v1[2], v1[3]));
    m0 = bmax(m0, red);
    m1 = bmax(m1, red);

    float e0[4], e1[4], sum0 = 0.f, sum1 = 0.f;
    #pragma unroll
    for (int j = 0; j < 4; ++j) {
        e0[j] = __expf(v0[j] - m0); sum0 += e0[j];
        e1[j] = __expf(v1[j] - m1); sum1 += e1[j];
    }
    sum0 = bsum(sum0, red);
    sum1 = bsum(sum1, red);
    float i0 = 0.5f / sum0, i1 = 0.5f / sum1;

    short4 o;
    o.x = f2bf(e0[0] * i0 + e1[0] * i1);
    o.y = f2bf(e0[1] * i0 + e1[1] * i1);
    o.z = f2bf(e0[2] * i0 + e1[2] * i1);
    o.w = f2bf(e0[3] * i0 + e1[3] * i1);
    *reinterpret_cast<short4*>(a + ((size_t)tag << 20) + (size_t)row * 1024 + t * 4) = o;
}

// ---------------- MLP1 split-K reduce: z1[tag] = bf16(relu(p0+p1+b)) --------
struct Ptr4 { const float* p[4]; };
__global__ __launch_bounds__(256) void mlp1_red_k(const float* __restrict__ zpart,
                                                  Ptr4 bias,
                                                  short* __restrict__ z1)
{
    int i = blockIdx.x * 256 + threadIdx.x;          // over 4*262144
    int tag = i >> 18, idx = i & 262143, col = i & 255;
    float s = bias.p[tag][col]
            + zpart[(size_t)(tag * 2 + 0) * 262144 + idx]
            + zpart[(size_t)(tag * 2 + 1) * 262144 + idx];
    z1[i] = f2bf(fmaxf(s, 0.f));
}

// ---------------- column standardize (ddof=1) + column softmax, batched ------
template<typename TOUT>
__global__ __launch_bounds__(256) void norm_softmax_b(const float* __restrict__ Zbase,
                                                      int zstride,
                                                      TOUT* __restrict__ Hout, int ldh,
                                                      int joffmul,
                                                      float* __restrict__ out2)
{
    __shared__ float red[256];
    const int j = blockIdx.x, t = threadIdx.x;
    const float* Z = Zbase + (size_t)blockIdx.y * zstride;
    const int joff = blockIdx.y * joffmul;

    float x[4];
    #pragma unroll
    for (int i = 0; i < 4; ++i) x[i] = Z[(size_t)(t + i * 256) * 256 + j];

    float s = x[0] + x[1] + x[2] + x[3];
    float mean = bsum(s, red) * (1.f / 1024.f);

    float ss = 0.f;
    #pragma unroll
    for (int i = 0; i < 4; ++i) { float d = x[i] - mean; ss += d * d; }
    float var = bsum(ss, red) * (1.f / 1023.f);
    float inv = 1.f / (sqrtf(var) + 1e-6f);

    float v[4];
    float mx = -3.4e38f;
    #pragma unroll
    for (int i = 0; i < 4; ++i) { v[i] = (x[i] - mean) * inv; mx = fmaxf(mx, v[i]); }
    mx = bmax(mx, red);

    float e[4], es = 0.f;
    #pragma unroll
    for (int i = 0; i < 4; ++i) { e[i] = __expf(v[i] - mx); es += e[i]; }
    es = bsum(es, red);
    float invs = 1.f / es;

    #pragma unroll
    for (int i = 0; i < 4; ++i) {
        float o = e[i] * invs;
        if constexpr (sizeof(TOUT) == 4)
            Hout[(size_t)(t + i * 256) * ldh + joff + j] = o;
        else
            Hout[(size_t)(t + i * 256) * ldh + joff + j] = f2bf(o);
        if (out2) out2[(size_t)(t + i * 256) * 256 + joff + j] = o;
    }
}

// ---------------- fusion split-K reduce: z1f = bf16(relu(sum_s + b)) ---------
__global__ __launch_bounds__(256) void freduce_k(const float* __restrict__ Cpartf,
                                                 const float* __restrict__ b,
                                                 short* __restrict__ z1f)
{
    int i = blockIdx.x * 256 + threadIdx.x;
    float s = b[i & 255];
    #pragma unroll
    for (int z = 0; z < 4; ++z) s += Cpartf[(size_t)z * 262144 + i];
    z1f[i] = f2bf(fmaxf(s, 0.f));
}

// ---------------- G split-K reduce ----------------
__global__ __launch_bounds__(256) void g_reduce_k(const float* __restrict__ Gpart,
                                                  float* __restrict__ G)
{
    int chain = blockIdx.y;
    int i = blockIdx.x * 256 + threadIdx.x;
    G[(size_t)chain * 131072 + i] =
        Gpart[(size_t)(chain * 2 + 0) * 131072 + i] +
        Gpart[(size_t)(chain * 2 + 1) * 131072 + i];
}

// ---------------- Cpart[s][j][k] = sum_{n in slab s(64)} H[n,j]*log(0.5*(H[n,j]+H[n,k]))
__global__ __launch_bounds__(256) void jsd_part_k(const float* __restrict__ H,
                                                  float* __restrict__ Cpart)
{
    __shared__ float hj[8][33];
    __shared__ float hk[8][33];
    const int t = threadIdx.x;
    const int tx = t & 15, ty = t >> 4;
    const int j0 = blockIdx.y * 32, k0 = blockIdx.x * 32;
    const int nbase = blockIdx.z * 64;

    float acc[2][2] = {};

    for (int c = 0; c < 8; ++c) {
        int n0 = nbase + c * 8;
        int nl = t >> 5, cc = t & 31;
        hj[nl][cc] = H[(size_t)(n0 + nl) * 256 + j0 + cc];
        hk[nl][cc] = H[(size_t)(n0 + nl) * 256 + k0 + cc];
        __syncthreads();
        #pragma unroll
        for (int nn = 0; nn < 8; ++nn) {
            float a0 = hj[nn][ty * 2], a1 = hj[nn][ty * 2 + 1];
            float b0 = hk[nn][tx * 2], b1 = hk[nn][tx * 2 + 1];
            acc[0][0] += a0 * __logf(0.5f * (a0 + b0));
            acc[0][1] += a0 * __logf(0.5f * (a0 + b1));
            acc[1][0] += a1 * __logf(0.5f * (a1 + b0));
            acc[1][1] += a1 * __logf(0.5f * (a1 + b1));
        }
        __syncthreads();
    }
    float* Cp = Cpart + (size_t)blockIdx.z * 65536;
    #pragma unroll
    for (int i = 0; i < 2; ++i)
        #pragma unroll
        for (int jj = 0; jj < 2; ++jj)
            Cp[(size_t)(j0 + ty * 2 + i) * 256 + k0 + tx * 2 + jj] = acc[i][jj];
}

// ---------------- per-k row/col sums over 16 slabs; ent[k] = diag(C) --------
__global__ __launch_bounds__(256) void rc_k(const float* __restrict__ Cpart,
                                            float* __restrict__ cmv,
                                            float* __restrict__ rmv,
                                            float* __restrict__ entv)
{
    __shared__ float red[256];
    const int k = blockIdx.x, j = threadIdx.x;
    float cm = 0.f, rm = 0.f;
    #pragma unroll
    for (int s = 0; s < 16; ++s) {
        cm += Cpart[(size_t)s * 65536 + (size_t)j * 256 + k];
        rm += Cpart[(size_t)s * 65536 + (size_t)k * 256 + j];
    }
    if (j == k) entv[k] = cm;   // C[k,k] = sum_n H[n,k]*log(H[n,k]) = ent[k]
    cm = bsum(cm, red);
    rm = bsum(rm, red);
    if (j == 0) { cmv[k] = cm; rmv[k] = rm; }
}

// ---------------- jm -> standardize -> softmax -> w ----------------
__global__ __launch_bounds__(256) void jmw_k(const float* __restrict__ cmv,
                                             const float* __restrict__ rmv,
                                             const float* __restrict__ ent,
                                             float* __restrict__ w)
{
    __shared__ float red[256];
    const int k = threadIdx.x;
    float e = ent[k];
    float esum = bsum(e, red);

    float jm = 0.5f * (esum * (1.f / 256.f) + e - (cmv[k] + rmv[k]) * (1.f / 256.f));

    float mean = bsum(jm, red) * (1.f / 256.f);
    float d = jm - mean;
    float var = bsum(d * d, red) * (1.f / 255.f);
    float v = d / (sqrtf(var) + 1e-6f);

    float mx = bmax(v, red);
    float ex = __expf(v - mx);
    float s = bsum(ex, red);
    w[k] = ex / s;
}

// ---------------- launch ----------------
extern "C" void kernel_launch(void* const* d_in, const int* in_sizes, int n_in,
                              void* d_out, int out_size, void* d_ws, size_t ws_size,
                              hipStream_t stream) {
    const float* x_time = (const float*)d_in[0];
    const float* x_news = (const float*)d_in[1];
    const float* f1w = (const float*)d_in[34];
    const float* f1b = (const float*)d_in[35];
    const float* f2w = (const float*)d_in[36];
    const float* f2b = (const float*)d_in[37];
    const float* theta_t = (const float*)d_in[38];
    const float* theta_n = (const float*)d_in[39];
    float* out = (float*)d_out;

    float* ws = (float*)d_ws;
    // region 0 [0 .. 2,097,152 fl): qk (8x524288 halves) -> a (4x1M halves) -> Hc
    short* s_qk = (short*)ws;
    short* s_a  = (short*)ws;                    // aliases qk (qk dead after scores)
    short* s_Hc = (short*)ws;                    // aliases a  (a dead after MLP1)
    // region 1 [2,097,152 .. 6,291,456 fl): S (8x1M halves) -> everything later
    short* s_S    = (short*)(ws + 2097152);      // 8 x 1048576 halves (16 MB)
    float* zpart  = ws + 2097152;                // 8 x 262144 fl (MLP1 split-K)
    short* s_z1   = (short*)(ws + 4194304);      // 4 x 262144 halves
    float* z2b    = ws + 4718592;                // 4 x 262144 fl
    float* Cpartf = ws + 2097152;                // 4 x 262144 fl (fusion, zpart dead)
    short* z1f    = s_z1;                        // slot 0 (z1 dead after MLP2)
    float* z2f    = z2b;                         // slot 0 (z2b dead after Hc)
    float* Cpart  = ws + 2097152;                // 16 x 65536 fl (jsd)
    float* entv   = ws + 3145728;                // smalls
    float* cmv    = entv + 256;
    float* rmv    = cmv + 256;
    float* wv     = rmv + 256;
    float* Gpart  = ws + 3407872;                // 4 x 131072 fl
    float* Gbuf   = ws + 3932160;                // 2 x 131072 fl
    float* Pbuf   = ws + 4194304;                // 2 x 524288 fl (z1/z2b dead)
    // persistent:
    float* Hbuf   = ws + 6291456;                // 262144 fl  (peak 26.2 MB)

    const float* qsrc[4]  = {x_time, x_news, x_time, x_news};
    const float* kvsrc[4] = {x_time, x_news, x_news, x_time};
    const int    base[4]  = {2, 10, 18, 26};

    Batch8 bp{};

    // ======== projections: z=8 {q_t,q_n,q_tn,q_nt,k_t,k_n,k_tn,k_nt} ========
    for (int tg = 0; tg < 4; ++tg) {
        bp.A[tg] = qsrc[tg];      bp.B[tg] = d_in[base[tg] + 0];
        bp.bias[tg] = (const float*)d_in[base[tg] + 2];
        bp.C[tg] = s_qk + (size_t)tg * 524288;
        bp.A[4 + tg] = kvsrc[tg]; bp.B[4 + tg] = d_in[base[tg] + 1];
        bp.bias[4 + tg] = (const float*)d_in[base[tg] + 3];
        bp.C[4 + tg] = s_qk + (size_t)(4 + tg) * 524288;
    }
    gemm_big_k<float, float, 1>
        <<<dim3(4, 8, 8), 256, 0, stream>>>(bp, 512, 512, 512, 512, 1.f);

    // ======== scores: z=8 (tag,head), S bf16, scale 1/16 ========
    for (int i = 0; i < 8; ++i) {
        int tg = i >> 1, h = i & 1;
        bp.A[i] = s_qk + (size_t)tg * 524288 + h * 256;
        bp.B[i] = s_qk + (size_t)(4 + tg) * 524288 + h * 256;
        bp.bias[i] = nullptr;
        bp.C[i] = s_S + ((size_t)i << 20);
    }
    gemm_big_k<short, short, 0>
        <<<dim3(8, 8, 8), 256, 0, stream>>>(bp, 512, 512, 1024, 256, 0.0625f);

    // ======== softmax + head mean -> a (bf16), all tags ========
    softmax_mean_b<<<4096, 256, 0, stream>>>(s_S, s_a);

    // ======== incidence MLP1: split-K z=8 (tag,half) ========
    for (int i = 0; i < 8; ++i) {
        int tg = i >> 1, hf = i & 1;
        bp.A[i] = s_a + ((size_t)tg << 20) + hf * 512;
        bp.B[i] = (const float*)d_in[base[tg] + 4] + hf * 512;
        bp.bias[i] = nullptr;
        bp.C[i] = zpart + (size_t)i * 262144;
    }
    gemm_b_k<short, float, float, false, false, 0>
        <<<dim3(4, 16, 8), 256, 0, stream>>>(bp, 1024, 1024, 256, 512, 1.f);
    Ptr4 b1{{(const float*)d_in[base[0] + 5], (const float*)d_in[base[1] + 5],
             (const float*)d_in[base[2] + 5], (const float*)d_in[base[3] + 5]}};
    mlp1_red_k<<<4096, 256, 0, stream>>>(zpart, b1, s_z1);

    // ======== incidence MLP2 z=4 ========
    for (int tg = 0; tg < 4; ++tg) {
        bp.A[tg] = s_z1 + (size_t)tg * 262144;
        bp.B[tg] = d_in[base[tg] + 6];
        bp.bias[tg] = (const float*)d_in[base[tg] + 7];
        bp.C[tg] = z2b + (size_t)tg * 262144;
    }
    gemm_b_k<short, float, float, false, false, 1>
        <<<dim3(4, 16, 4), 256, 0, stream>>>(bp, 256, 256, 256, 256, 1.f);

    // norm_softmax over 4 tags -> Hcat (bf16)
    norm_softmax_b<short><<<dim3(256, 4), 256, 0, stream>>>(z2b, 262144, s_Hc, 1024, 256, nullptr);

    // ======== fusion MLP (split-K z=4) + norm_softmax -> Hbuf (+out H) ========
    for (int z = 0; z < 4; ++z) {
        bp.A[z] = s_Hc + z * 256;
        bp.B[z] = f1w + z * 256;
        bp.bias[z] = nullptr;
        bp.C[z] = Cpartf + (size_t)z * 262144;
    }
    gemm_b_k<short, float, float, false, false, 0>
        <<<dim3(4, 16, 4), 256, 0, stream>>>(bp, 1024, 1024, 256, 256, 1.f);
    freduce_k<<<1024, 256, 0, stream>>>(Cpartf, f1b, z1f);

    bp.A[0] = z1f; bp.B[0] = f2w; bp.bias[0] = f2b; bp.C[0] = z2f;
    gemm_b_k<short, float, float, false, false, 1>
        <<<dim3(4, 16, 1), 256, 0, stream>>>(bp, 256, 256, 256, 256, 1.f);
    norm_softmax_b<float><<<dim3(256, 1), 256, 0, stream>>>(z2f, 0, Hbuf, 256, 0,
                                                            out + 1048576);

    // ======== JSD -> w ========
    jsd_part_k<<<dim3(8, 8, 16), 256, 0, stream>>>(Hbuf, Cpart);
    rc_k<<<256, 256, 0, stream>>>(Cpart, cmv, rmv, entv);
    jmw_k<<<1, 256, 0, stream>>>(cmv, rmv, entv, wv);

    // ======== finals: G = H^T X (split-K), P = (H*w) G, out = x + elu(P theta) ==
    const float* xc[2] = {x_time, x_news};
    const float* th[2] = {theta_t, theta_n};
    for (int i = 0; i < 4; ++i) {                 // i = chain*2 + slab
        int chain = i >> 1, slab = i & 1;
        bp.A[i] = Hbuf + (size_t)slab * 512 * 256;
        bp.B[i] = xc[chain] + (size_t)slab * 512 * 512;
        bp.bias[i] = nullptr;
        bp.C[i] = Gpart + (size_t)i * 131072;
    }
    gemm_b_k<float, float, float, true, true, 0>
        <<<dim3(8, 4, 4), 256, 0, stream>>>(bp, 256, 512, 512, 512, 1.f);
    g_reduce_k<<<dim3(512, 2), 256, 0, stream>>>(Gpart, Gbuf);

    for (int c = 0; c < 2; ++c) {
        bp.A[c] = Hbuf;                            // wscale applies w[k]
        bp.B[c] = Gbuf + (size_t)c * 131072;
        bp.bias[c] = nullptr;
        bp.C[c] = Pbuf + (size_t)c * 524288;
    }
    gemm_b_k<float, float, float, false, true, 0, true>
        <<<dim3(8, 16, 2), 256, 0, stream>>>(bp, 256, 512, 512, 256, 1.f, wv);

    for (int c = 0; c < 2; ++c) {
        bp.A[c] = Pbuf + (size_t)c * 524288;
        bp.B[c] = th[c];
        bp.bias[c] = nullptr;
        bp.add[c] = xc[c];
        bp.C[c] = out + (size_t)c * 524288;
    }
    gemm_b_k<float, float, float, false, true, 3>
        <<<dim3(8, 16, 2), 256, 0, stream>>>(bp, 512, 512, 512, 512, 1.f);
}